// Round 3
// baseline (2100.656 us; speedup 1.0000x reference)
//
#include <hip/hip_runtime.h>

#define NN 1024
#define BT 32
#define TT 32
#define NTILES ((TT * (TT + 1)) / 2)   // 528

// ---------------------------------------------------------------------------
// Fence-free cross-XCD protocol, fully BATCHED both directions.
// All R/C traffic bypasses L1/L2 (sc0 sc1 -> MALL = coherence point).
// Loads AND stores are inline-asm issued back-to-back; exactly one
// s_waitcnt vmcnt(N) per batch. No buffer_inv / buffer_wbl2 anywhere.
// Flag polls load all flags in ONE asm block (single RTT per poll iter).
// ---------------------------------------------------------------------------
__device__ __forceinline__ double gload_cc(const double* p) {
    double v;
    asm volatile("global_load_dwordx2 %0, %1, off sc0 sc1" : "=v"(v) : "v"(p));
    return v;
}
__device__ __forceinline__ void gstore_cc(double* p, double v) {
    asm volatile("global_store_dwordx2 %0, %1, off sc0 sc1" :: "v"(p), "v"(v));
}
__device__ __forceinline__ void gstore_flag(int* p, int v) {
    asm volatile("global_store_dword %0, %1, off sc0 sc1" :: "v"(p), "v"(v));
}
#define VWAIT0 asm volatile("s_waitcnt vmcnt(0)" ::: "memory")
#define VWAIT2 asm volatile("s_waitcnt vmcnt(2)" ::: "memory")

__device__ __forceinline__ void waitflag2(const int* f, int a0, int b0, int a1, int b1) {
    const int* p0 = &f[(a0 * TT + b0) << 4];
    const int* p1 = &f[(a1 * TT + b1) << 4];
    while (true) {
        int v0, v1;
        asm volatile("global_load_dword %0, %2, off sc0 sc1\n\t"
                     "global_load_dword %1, %3, off sc0 sc1\n\t"
                     "s_waitcnt vmcnt(0)"
                     : "=&v"(v0), "=&v"(v1)
                     : "v"(p0), "v"(p1));
        if (v0 & v1) break;
        __builtin_amdgcn_s_sleep(1);
    }
    asm volatile("" ::: "memory");
}
__device__ __forceinline__ void waitflag4(const int* f, int a0, int b0, int a1, int b1,
                                          int a2, int b2, int a3, int b3) {
    const int* p0 = &f[(a0 * TT + b0) << 4];
    const int* p1 = &f[(a1 * TT + b1) << 4];
    const int* p2 = &f[(a2 * TT + b2) << 4];
    const int* p3 = &f[(a3 * TT + b3) << 4];
    while (true) {
        int v0, v1, v2, v3;
        asm volatile("global_load_dword %0, %4, off sc0 sc1\n\t"
                     "global_load_dword %1, %5, off sc0 sc1\n\t"
                     "global_load_dword %2, %6, off sc0 sc1\n\t"
                     "global_load_dword %3, %7, off sc0 sc1\n\t"
                     "s_waitcnt vmcnt(0)"
                     : "=&v"(v0), "=&v"(v1), "=&v"(v2), "=&v"(v3)
                     : "v"(p0), "v"(p1), "v"(p2), "v"(p3));
        if (v0 & v1 & v2 & v3) break;
        __builtin_amdgcn_s_sleep(1);
    }
    asm volatile("" ::: "memory");
}
__device__ __forceinline__ void setflag(int* f, int a, int b) {
    VWAIT0;                                   // all data stores at coherence point
    gstore_flag(&f[(a * TT + b) << 4], 1);
}

// ---------------------------------------------------------------------------
__global__ void primes_kernel(const float* __restrict__ feat, int* __restrict__ primes) {
    int i = blockIdx.x * blockDim.x + threadIdx.x;
    if (i < NN) {
        float best = feat[i * NN];
        int arg = 0;
        for (int ch = 1; ch < 4; ++ch) {
            float v = feat[ch * NN * NN + i * NN];
            if (v > best) { best = v; arg = ch; }
        }
        const int P[4] = {2, 3, 5, 7};
        primes[i] = P[arg];
    }
}

__global__ void prep_kernel(const float* __restrict__ con, const int* __restrict__ primes,
                            float* __restrict__ S, double* __restrict__ R,
                            double* __restrict__ C, float* __restrict__ out,
                            int* __restrict__ flags) {
    int idx = blockIdx.x * blockDim.x + threadIdx.x;
    int i = idx >> 10;
    int j = idx & (NN - 1);
    float c = (con[idx] + con[j * NN + i]) * 0.5f;
    int prod = primes[i] * primes[j];
    bool canon = (prod == 14) | (prod == 15) | (prod == 35);
    int d = i - j; if (d < 0) d = -d;
    S[idx] = (canon && d >= 4) ? c : 0.0f;
    R[idx] = 0.0;
    C[idx] = 0.0;
    out[idx] = 0.0f;
    if (idx < TT * TT * 16) flags[idx] = 0;
}

// ---------------------------------------------------------------------------
// Dataflow DP, one wave per 32x32 tile. Exactness: every candidate is one
// fp64 add of stored values; extra candidates are dominated (-1e30+x<0<=dp,
// stale-0 + 0 = 0 <= dp). fmax order-insensitive => DP bitwise == numpy.
// ---------------------------------------------------------------------------
__global__ __launch_bounds__(64) void nuss_tiles_kernel(double* __restrict__ R,
                                                        double* __restrict__ C,
                                                        const float* __restrict__ S,
                                                        int* __restrict__ flags) {
    __shared__ double DJJc[32][33];                         // DJJc[c][m]=V(aJ+m,aJ+c); [32]=0
    __shared__ double Vtc[32][33];                          // Vtc[c][r]=V(aI+r,aJ+c); [32]=edge
    __shared__ __attribute__((aligned(16))) double Ast[32][34]; // Ast[kk][r]=V(aI+r,kt0+kk)
    __shared__ __attribute__((aligned(16))) double Bst[32][34]; // Bst[kk][c]=V(kt0+kk+1,aJ+c)
    __shared__ double Pld[32][33];
    __shared__ float  Sld[32][32];
    __shared__ double edgeCol[33];                          // V(aI+rr, aJ-1)

    int b = blockIdx.x, dd = 0;
    while (b >= TT - dd) { b -= TT - dd; ++dd; }
    const int I = b, J = b + dd;
    const int aI = I * BT, aJ = J * BT;
    const int lane = threadIdx.x;
    const int r = lane >> 1;
    const int h = lane & 1;

    if (dd == 0) {
        // ---------------- diagonal tile ----------------
        for (int w = 0; w < 16; ++w) {
            int idx = w * 64 + lane; int rr = idx >> 5, cc = idx & 31;
            Sld[rr][cc] = S[(aI + rr) * NN + aI + cc];
        }
        for (int idx = lane; idx < 32 * 33; idx += 64)
            ((double*)Vtc)[idx] = 0.0;
        double vrow[16];
        #pragma unroll
        for (int u = 0; u < 16; ++u) vrow[u] = 0.0;

        for (int s = 1; s <= 31; ++s) {
            int c = r + s;
            bool act = (c <= 31);
            double acc = 0.0;
            if (act) {
                double t0 = 0.0, t1 = 0.0, t2 = 0.0, t3 = 0.0;
                #pragma unroll
                for (int u = 0; u < 16; u += 4) {
                    int k0 = h * 16 + u;
                    t0 = fmax(t0, vrow[u]     + Vtc[c][k0 + 1]);
                    t1 = fmax(t1, vrow[u + 1] + Vtc[c][k0 + 2]);
                    t2 = fmax(t2, vrow[u + 2] + Vtc[c][k0 + 3]);
                    t3 = fmax(t3, vrow[u + 3] + Vtc[c][k0 + 4]);
                }
                acc = fmax(fmax(t0, t1), fmax(t2, t3));
            }
            acc = fmax(acc, __shfl_xor(acc, 1));
            if (act) {
                double best = fmax(acc, Vtc[c - 1][r + 1] + (double)Sld[r][c]);
                if (h == 0) Vtc[c][r] = best;
                #pragma unroll
                for (int u = 0; u < 16; ++u)
                    if (h * 16 + u == c) vrow[u] = best;
            }
        }
        for (int w = 0; w < 16; ++w) {
            int idx = w * 64 + lane; int rr = idx >> 5, cc = idx & 31;
            gstore_cc(&R[(aI + rr) * NN + aI + cc], Vtc[cc][rr]);
        }
        for (int w = 0; w < 16; ++w) {
            int idx = w * 64 + lane; int cc = idx >> 5, rr = idx & 31;
            gstore_cc(&C[(aI + cc) * NN + aI + rr], Vtc[cc][rr]);
        }
        if (lane == 0) setflag(flags, I, I);
        else VWAIT0;
        return;
    }

    // ---------------- off-diagonal tile ----------------
    waitflag2(flags, I, I, J, J);

    // Batched MALL loads: DJJc (16/lane) + aslice (16/lane); Sld/Vtc-zero
    // overlap the flight time; single vmcnt(0).
    double ra[16], rb[16];
    #pragma unroll
    for (int w = 0; w < 16; ++w) {
        int idx = w * 64 + lane; int cc = idx >> 5, mm = idx & 31;
        ra[w] = gload_cc(&C[(aJ + cc) * NN + aJ + mm]);
    }
    #pragma unroll
    for (int u = 0; u < 16; ++u) {
        int kk = h * 16 + u;
        rb[u] = gload_cc(&R[(aI + r) * NN + aI + kk]);
    }
    for (int w = 0; w < 16; ++w) {
        int idx = w * 64 + lane; int rr = idx >> 5, cc = idx & 31;
        Sld[rr][cc] = S[(aI + rr) * NN + aJ + cc];
    }
    for (int idx = lane; idx < 32 * 33; idx += 64)
        ((double*)Vtc)[idx] = 0.0;
    VWAIT0;
    #pragma unroll
    for (int w = 0; w < 16; ++w) {
        int idx = w * 64 + lane; int cc = idx >> 5, mm = idx & 31;
        DJJc[cc][mm] = ra[w];
    }
    if (lane < 32) DJJc[lane][32] = 0.0;

    double aslice[16];
    #pragma unroll
    for (int u = 0; u < 16; ++u) {
        int kk = h * 16 + u;
        aslice[u] = (kk >= r) ? rb[u] : -1.0e30;
    }

    // ---- phaseA: middle-out k-tile order, readiness-aligned PAIRS ----
    double P[16];
    #pragma unroll
    for (int x = 0; x < 16; ++x) P[x] = 0.0;
    const int nk = dd - 1;
    const int rg = lane >> 3, cg = lane & 7;
    const int r4 = rg * 4, c4 = cg * 4;

    auto kkloop = [&]() {
        for (int kk = 0; kk < 32; ++kk) {
            double2 av0 = *(const double2*)&Ast[kk][r4];
            double2 av1 = *(const double2*)&Ast[kk][r4 + 2];
            double2 bv0 = *(const double2*)&Bst[kk][c4];
            double2 bv1 = *(const double2*)&Bst[kk][c4 + 2];
            P[0]  = fmax(P[0],  av0.x + bv0.x); P[1]  = fmax(P[1],  av0.x + bv0.y);
            P[2]  = fmax(P[2],  av0.x + bv1.x); P[3]  = fmax(P[3],  av0.x + bv1.y);
            P[4]  = fmax(P[4],  av0.y + bv0.x); P[5]  = fmax(P[5],  av0.y + bv0.y);
            P[6]  = fmax(P[6],  av0.y + bv1.x); P[7]  = fmax(P[7],  av0.y + bv1.y);
            P[8]  = fmax(P[8],  av1.x + bv0.x); P[9]  = fmax(P[9],  av1.x + bv0.y);
            P[10] = fmax(P[10], av1.x + bv1.x); P[11] = fmax(P[11], av1.x + bv1.y);
            P[12] = fmax(P[12], av1.y + bv0.x); P[13] = fmax(P[13], av1.y + bv0.y);
            P[14] = fmax(P[14], av1.y + bv1.x); P[15] = fmax(P[15], av1.y + bv1.y);
        }
    };
    // proc(t1, t2): wait flags (merged), stage t1, issue t2 loads in flight
    // under t1's kk-loop, then drain + stage + compute t2.
    auto proc = [&](int t1, int t2) {
        if (t2 >= 0) waitflag4(flags, I, t1, t1, J, I, t2, t2, J);
        else         waitflag2(flags, I, t1, t1, J);
        int k1 = t1 * BT;
        #pragma unroll
        for (int w = 0; w < 16; ++w) {
            int idx = w * 64 + lane; int rr = idx >> 5, kk = idx & 31;
            ra[w] = gload_cc(&R[(aI + rr) * NN + k1 + kk]);
            rb[w] = gload_cc(&C[(aJ + rr) * NN + k1 + 1 + kk]);
        }
        VWAIT0;
        #pragma unroll
        for (int w = 0; w < 16; ++w) {
            int idx = w * 64 + lane; int rr = idx >> 5, kk = idx & 31;
            Ast[kk][rr] = ra[w];
            Bst[kk][rr] = rb[w];
        }
        if (t2 >= 0) {
            int k2 = t2 * BT;
            #pragma unroll
            for (int w = 0; w < 16; ++w) {
                int idx = w * 64 + lane; int rr = idx >> 5, kk = idx & 31;
                ra[w] = gload_cc(&R[(aI + rr) * NN + k2 + kk]);
                rb[w] = gload_cc(&C[(aJ + rr) * NN + k2 + 1 + kk]);
            }
        }
        kkloop();
        if (t2 >= 0) {
            VWAIT0;
            #pragma unroll
            for (int w = 0; w < 16; ++w) {
                int idx = w * 64 + lane; int rr = idx >> 5, kk = idx & 31;
                Ast[kk][rr] = ra[w];
                Bst[kk][rr] = rb[w];
            }
            kkloop();
        }
    };

    {
        int tl = (I + J) >> 1, tr = ((I + J) >> 1) + 1;
        int pend = -1;
        for (int q = 0; q < nk; ++q) {
            int t;
            if ((q & 1) == 0) { if (tl >= I + 1) t = tl--; else t = tr++; }
            else              { if (tr <= J - 1) t = tr++; else t = tl--; }
            if (pend < 0) { pend = t; continue; }
            int rp = (pend - I > J - pend) ? pend - I : J - pend;
            int rt = (t - I > J - t) ? t - I : J - t;
            if (rp == rt) { proc(pend, t); pend = -1; }
            else          { proc(pend, -1); pend = t; }
        }
        if (pend >= 0) proc(pend, -1);
    }

    if (nk > 0) {
        #pragma unroll
        for (int x = 0; x < 4; ++x)
            #pragma unroll
            for (int y = 0; y < 4; ++y)
                Pld[r4 + x][c4 + y] = P[x * 4 + y];
    } else {
        for (int idx = lane; idx < 32 * 33; idx += 64)
            ((double*)Pld)[idx] = 0.0;
    }

    // ---- edges (flags covered: dd==1 by diag waits; dd>=2 by k-loop) ----
    double ec = 0.0, ve = 0.0;
    if (lane < 33) ec = gload_cc(&R[(aI + lane) * NN + (aJ - 1)]);
    if (lane < 32) ve = gload_cc(&R[(aI + 32) * NN + aJ + lane]);
    VWAIT0;
    if (lane < 33) edgeCol[lane] = ec;
    if (lane < 32) Vtc[lane][32] = ve;

    // ---- phaseB: 63 anti-diagonal micro-steps, barrier-free ----
    double vrow[16];
    #pragma unroll
    for (int u = 0; u < 16; ++u) vrow[u] = 0.0;

    for (int s = 0; s < 63; ++s) {
        int c = r + s - 31;
        bool act = ((unsigned)c < 32u);
        double acc = -1.0e30;
        if (act) {
            double t0 = -1.0e30, t1 = -1.0e30, t2 = -1.0e30, t3 = -1.0e30;
            #pragma unroll
            for (int u = 0; u < 16; u += 4) {
                int k0 = h * 16 + u;
                t0 = fmax(t0, aslice[u]     + Vtc[c][k0 + 1]);
                t1 = fmax(t1, aslice[u + 1] + Vtc[c][k0 + 2]);
                t2 = fmax(t2, aslice[u + 2] + Vtc[c][k0 + 3]);
                t3 = fmax(t3, aslice[u + 3] + Vtc[c][k0 + 4]);
            }
            double q0 = -1.0e30, q1 = -1.0e30, q2 = -1.0e30, q3 = -1.0e30;
            #pragma unroll
            for (int u = 0; u < 16; u += 4) {
                int m0 = h * 16 + u + 1;
                q0 = fmax(q0, vrow[u]     + DJJc[c][m0]);
                q1 = fmax(q1, vrow[u + 1] + DJJc[c][m0 + 1]);
                q2 = fmax(q2, vrow[u + 2] + DJJc[c][m0 + 2]);
                q3 = fmax(q3, vrow[u + 3] + DJJc[c][m0 + 3]);
            }
            acc = fmax(fmax(fmax(t0, t1), fmax(t2, t3)),
                       fmax(fmax(q0, q1), fmax(q2, q3)));
        }
        acc = fmax(acc, __shfl_xor(acc, 1));
        if (act) {
            double best = acc;
            best = fmax(best, edgeCol[r] + DJJc[c][0]);      // k = aJ-1
            best = fmax(best, Pld[r][c]);                    // external k-tiles
            double pv = (c > 0) ? Vtc[c - 1][r + 1] : edgeCol[r + 1];
            best = fmax(best, pv + (double)Sld[r][c]);       // pair
            if (h == 0) Vtc[c][r] = best;
            #pragma unroll
            for (int u = 0; u < 16; ++u)
                if (h * 16 + u == c) vrow[u] = best;
        }
    }

    for (int w = 0; w < 16; ++w) {
        int idx = w * 64 + lane; int rr = idx >> 5, cc = idx & 31;
        gstore_cc(&R[(aI + rr) * NN + aJ + cc], Vtc[cc][rr]);
    }
    for (int w = 0; w < 16; ++w) {
        int idx = w * 64 + lane; int cc = idx >> 5, rr = idx & 31;
        gstore_cc(&C[(aJ + cc) * NN + aI + rr], Vtc[cc][rr]);
    }
    if (lane == 0) setflag(flags, I, J);
    else VWAIT0;
}

// ---------------------------------------------------------------------------
// Traceback, software-pipelined: successor operands are loaded BEFORE the
// branch decision, hiding one L2 latency per event. Semantics unchanged.
// ---------------------------------------------------------------------------
__global__ __launch_bounds__(256) void traceback_kernel(const double* __restrict__ R,
                                                        const double* __restrict__ C,
                                                        const float* __restrict__ S,
                                                        float* __restrict__ out) {
    __shared__ int stk_i[2048];
    __shared__ int stk_j[2048];
    __shared__ double stk_v[2048];
    __shared__ int sh_top, sh_ii, sh_jj, sh_cmd;
    __shared__ double sred_v[4];
    __shared__ int sred_k[4];
    const double eps = 1e-9;
    if (threadIdx.x == 0) {
        sh_top = 1; stk_i[0] = 0; stk_j[0] = NN - 1; stk_v[0] = R[NN - 1];
    }
    __syncthreads();
    while (true) {
        if (threadIdx.x == 0) {
            int cmd = -1, top = sh_top;
            int i = 0, j = 0; double v = 0.0, a = 0.0, b2 = 0.0; float sv = 0.0f;
            bool have = false;
            while (true) {
                if (!have) {
                    if (top == 0) { cmd = -1; break; }
                    i = stk_i[--top]; j = stk_j[top]; v = stk_v[top];
                    if (j <= i || v <= eps) continue;
                    a  = R[(i + 1) * NN + j];
                    sv = S[i * NN + j];
                    b2 = R[(i + 1) * NN + j - 1];
                    have = true;
                    continue;
                }
                int ip = (i + 2 <= NN - 1) ? i + 2 : NN - 1;    // clamp (unused if OOB)
                int jl = (j - 2 >= 0) ? j - 2 : 0;
                double ar = R[ip * NN + j];
                double br = R[ip * NN + j - 1];
                double bl = R[ip * NN + jl];
                float  sr = S[(i + 1) * NN + j];
                float  sl = S[(i + 1) * NN + j - 1];
                if (a >= v - eps) {
                    ++i; v = a; a = ar; sv = sr; b2 = br;
                    if (j <= i || v <= eps) have = false;
                    continue;
                }
                if (sv > 0.0f && b2 + (double)sv >= v - eps) {
                    out[i * NN + j] = sv; out[j * NN + i] = sv;
                    ++i; --j; v = b2; a = br; sv = sl; b2 = bl;
                    if (j <= i || v <= eps) have = false;
                    continue;
                }
                sh_ii = i; sh_jj = j; cmd = 0; break;
            }
            sh_top = top; sh_cmd = cmd;
        }
        __syncthreads();
        if (sh_cmd < 0) break;
        int i = sh_ii, j = sh_jj;
        double bv = -1.0; int bk = 0x7fffffff;
        for (int k = i + threadIdx.x; k < j; k += 256) {
            double tv = R[i * NN + k] + C[j * NN + k + 1];
            if (tv > bv) { bv = tv; bk = k; }
        }
        for (int off = 32; off; off >>= 1) {
            double ov = __shfl_down(bv, off);
            int   ok = __shfl_down(bk, off);
            if (ov > bv || (ov == bv && ok < bk)) { bv = ov; bk = ok; }
        }
        if ((threadIdx.x & 63) == 0) { sred_v[threadIdx.x >> 6] = bv; sred_k[threadIdx.x >> 6] = bk; }
        __syncthreads();
        if (threadIdx.x == 0) {
            double fv = sred_v[0]; int fk = sred_k[0];
            for (int w = 1; w < 4; ++w)
                if (sred_v[w] > fv || (sred_v[w] == fv && sred_k[w] < fk)) { fv = sred_v[w]; fk = sred_k[w]; }
            int top = sh_top;
            stk_i[top] = sh_ii;  stk_j[top] = fk;    stk_v[top] = R[sh_ii * NN + fk];      ++top;
            stk_i[top] = fk + 1; stk_j[top] = sh_jj; stk_v[top] = C[sh_jj * NN + fk + 1];  ++top;
            sh_top = top;
        }
        __syncthreads();
    }
}

// ---------------------------------------------------------------------------
extern "C" void kernel_launch(void* const* d_in, const int* in_sizes, int n_in,
                              void* d_out, int out_size, void* d_ws, size_t ws_size,
                              hipStream_t stream) {
    const float* con  = (const float*)d_in[0];
    const float* feat = (const float*)d_in[1];
    float* out = (float*)d_out;

    char* ws = (char*)d_ws;
    double* R      = (double*)(ws);
    double* C      = (double*)(ws + (size_t)8  * 1024 * 1024);
    float*  S      = (float*) (ws + (size_t)16 * 1024 * 1024);
    int*    primes = (int*)   (ws + (size_t)20 * 1024 * 1024);
    int*    flags  = (int*)   (ws + (size_t)20 * 1024 * 1024 + 8192);

    primes_kernel<<<(NN + 255) / 256, 256, 0, stream>>>(feat, primes);
    prep_kernel<<<(NN * NN) / 256, 256, 0, stream>>>(con, primes, S, R, C, out, flags);
    nuss_tiles_kernel<<<NTILES, 64, 0, stream>>>(R, C, S, flags);
    traceback_kernel<<<1, 256, 0, stream>>>(R, C, S, out);
}

// Round 4
// 2099.853 us; speedup vs baseline: 1.0004x; 1.0004x over previous
//
#include <hip/hip_runtime.h>

#define NN 1024
#define BT 32
#define TT 32
#define NTILES ((TT * (TT + 1)) / 2)   // 528

// ---------------------------------------------------------------------------
// Fence-free cross-XCD protocol, fully BATCHED both directions.
// All R/C traffic bypasses L1/L2 (sc0 sc1 -> MALL = coherence point).
// Loads AND stores are inline-asm issued back-to-back; one s_waitcnt per
// batch. Polls are ACTIVE-SPIN: a loop-carried v_fma_f64 chain (~200 cy)
// replaces s_sleep, keeping the SIMDs issuing so DPM holds high SCLK
// (clock-throttle falsification test; waves are 98% waiting otherwise).
// ---------------------------------------------------------------------------
__device__ __forceinline__ double gload_cc(const double* p) {
    double v;
    asm volatile("global_load_dwordx2 %0, %1, off sc0 sc1" : "=v"(v) : "v"(p));
    return v;
}
__device__ __forceinline__ void gstore_cc(double* p, double v) {
    asm volatile("global_store_dwordx2 %0, %1, off sc0 sc1" :: "v"(p), "v"(v));
}
__device__ __forceinline__ void gstore_flag(int* p, int v) {
    asm volatile("global_store_dword %0, %1, off sc0 sc1" :: "v"(p), "v"(v));
}
#define VWAIT0 asm volatile("s_waitcnt vmcnt(0)" ::: "memory")

__device__ __forceinline__ void waitflag2(const int* f, int a0, int b0, int a1, int b1) {
    const int* p0 = &f[(a0 * TT + b0) << 4];
    const int* p1 = &f[(a1 * TT + b1) << 4];
    double x = (double)(unsigned long long)p0;   // opaque seed: not foldable
    while (true) {
        int v0, v1;
        asm volatile("global_load_dword %0, %2, off sc0 sc1\n\t"
                     "global_load_dword %1, %3, off sc0 sc1\n\t"
                     "s_waitcnt vmcnt(0)"
                     : "=&v"(v0), "=&v"(v1)
                     : "v"(p0), "v"(p1));
        if (v0 & v1) break;
        #pragma unroll
        for (int i = 0; i < 24; ++i) x = fma(x, 1.0000000001, 1.0e-300);
    }
    asm volatile("" :: "v"(x));      // keep the chain live (loop-carried)
    asm volatile("" ::: "memory");
}
__device__ __forceinline__ void waitflag4(const int* f, int a0, int b0, int a1, int b1,
                                          int a2, int b2, int a3, int b3) {
    const int* p0 = &f[(a0 * TT + b0) << 4];
    const int* p1 = &f[(a1 * TT + b1) << 4];
    const int* p2 = &f[(a2 * TT + b2) << 4];
    const int* p3 = &f[(a3 * TT + b3) << 4];
    double x = (double)(unsigned long long)p0;
    while (true) {
        int v0, v1, v2, v3;
        asm volatile("global_load_dword %0, %4, off sc0 sc1\n\t"
                     "global_load_dword %1, %5, off sc0 sc1\n\t"
                     "global_load_dword %2, %6, off sc0 sc1\n\t"
                     "global_load_dword %3, %7, off sc0 sc1\n\t"
                     "s_waitcnt vmcnt(0)"
                     : "=&v"(v0), "=&v"(v1), "=&v"(v2), "=&v"(v3)
                     : "v"(p0), "v"(p1), "v"(p2), "v"(p3));
        if (v0 & v1 & v2 & v3) break;
        #pragma unroll
        for (int i = 0; i < 24; ++i) x = fma(x, 1.0000000001, 1.0e-300);
    }
    asm volatile("" :: "v"(x));
    asm volatile("" ::: "memory");
}

// ---------------------------------------------------------------------------
__global__ void primes_kernel(const float* __restrict__ feat, int* __restrict__ primes) {
    int i = blockIdx.x * blockDim.x + threadIdx.x;
    if (i < NN) {
        float best = feat[i * NN];
        int arg = 0;
        for (int ch = 1; ch < 4; ++ch) {
            float v = feat[ch * NN * NN + i * NN];
            if (v > best) { best = v; arg = ch; }
        }
        const int P[4] = {2, 3, 5, 7};
        primes[i] = P[arg];
    }
}

__global__ void prep_kernel(const float* __restrict__ con, const int* __restrict__ primes,
                            float* __restrict__ S, double* __restrict__ R,
                            double* __restrict__ C, float* __restrict__ out,
                            int* __restrict__ flags) {
    int idx = blockIdx.x * blockDim.x + threadIdx.x;
    int i = idx >> 10;
    int j = idx & (NN - 1);
    float c = (con[idx] + con[j * NN + i]) * 0.5f;
    int prod = primes[i] * primes[j];
    bool canon = (prod == 14) | (prod == 15) | (prod == 35);
    int d = i - j; if (d < 0) d = -d;
    S[idx] = (canon && d >= 4) ? c : 0.0f;
    R[idx] = 0.0;
    C[idx] = 0.0;
    out[idx] = 0.0f;
    if (idx < TT * TT * 16) flags[idx] = 0;
}

// ---------------------------------------------------------------------------
// Dataflow DP, one wave per 32x32 tile. Exactness: every candidate is one
// fp64 add of stored values; extra candidates are dominated (-1e30+x<0<=dp,
// stale-0 + 0 = 0 <= dp). fmax order-insensitive => DP bitwise == numpy.
// ---------------------------------------------------------------------------
__global__ __launch_bounds__(64) void nuss_tiles_kernel(double* __restrict__ R,
                                                        double* __restrict__ C,
                                                        const float* __restrict__ S,
                                                        int* __restrict__ flags) {
    __shared__ double DJJc[32][33];                         // DJJc[c][m]=V(aJ+m,aJ+c); [32]=0
    __shared__ double Vtc[32][33];                          // Vtc[c][r]=V(aI+r,aJ+c); [32]=edge
    __shared__ __attribute__((aligned(16))) double Ast[32][34]; // Ast[kk][r]=V(aI+r,kt0+kk)
    __shared__ __attribute__((aligned(16))) double Bst[32][34]; // Bst[kk][c]=V(kt0+kk+1,aJ+c)
    __shared__ double Pld[32][33];
    __shared__ float  Sld[32][32];
    __shared__ double edgeCol[33];                          // V(aI+rr, aJ-1)

    int b = blockIdx.x, dd = 0;
    while (b >= TT - dd) { b -= TT - dd; ++dd; }
    const int I = b, J = b + dd;
    const int aI = I * BT, aJ = J * BT;
    const int lane = threadIdx.x;
    const int r = lane >> 1;
    const int h = lane & 1;

    if (dd == 0) {
        // ---------------- diagonal tile ----------------
        for (int w = 0; w < 16; ++w) {
            int idx = w * 64 + lane; int rr = idx >> 5, cc = idx & 31;
            Sld[rr][cc] = S[(aI + rr) * NN + aI + cc];
        }
        for (int idx = lane; idx < 32 * 33; idx += 64)
            ((double*)Vtc)[idx] = 0.0;
        double vrow[16];
        #pragma unroll
        for (int u = 0; u < 16; ++u) vrow[u] = 0.0;

        for (int s = 1; s <= 31; ++s) {
            int c = r + s;
            bool act = (c <= 31);
            double acc = 0.0;
            if (act) {
                double t0 = 0.0, t1 = 0.0, t2 = 0.0, t3 = 0.0;
                #pragma unroll
                for (int u = 0; u < 16; u += 4) {
                    int k0 = h * 16 + u;
                    t0 = fmax(t0, vrow[u]     + Vtc[c][k0 + 1]);
                    t1 = fmax(t1, vrow[u + 1] + Vtc[c][k0 + 2]);
                    t2 = fmax(t2, vrow[u + 2] + Vtc[c][k0 + 3]);
                    t3 = fmax(t3, vrow[u + 3] + Vtc[c][k0 + 4]);
                }
                acc = fmax(fmax(t0, t1), fmax(t2, t3));
            }
            acc = fmax(acc, __shfl_xor(acc, 1));
            if (act) {
                double best = fmax(acc, Vtc[c - 1][r + 1] + (double)Sld[r][c]);
                if (h == 0) Vtc[c][r] = best;
                #pragma unroll
                for (int u = 0; u < 16; ++u)
                    if (h * 16 + u == c) vrow[u] = best;
            }
        }
        for (int w = 0; w < 16; ++w) {
            int idx = w * 64 + lane; int rr = idx >> 5, cc = idx & 31;
            gstore_cc(&R[(aI + rr) * NN + aI + cc], Vtc[cc][rr]);
        }
        for (int w = 0; w < 16; ++w) {
            int idx = w * 64 + lane; int cc = idx >> 5, rr = idx & 31;
            gstore_cc(&C[(aI + cc) * NN + aI + rr], Vtc[cc][rr]);
        }
        VWAIT0;                                   // data at coherence point
        if (lane == 0) gstore_flag(&flags[(I * TT + I) << 4], 1);
        return;
    }

    // ---------------- off-diagonal tile ----------------
    const int nk = dd - 1;
    waitflag2(flags, I, I, J, J);

    // Batched MALL loads: DJJc (16/lane) + aslice (16/lane); Sld/Vtc-zero
    // overlap the flight time; single vmcnt(0). For dd==1 the edge loads
    // ride in the same batch (their producers are the two diag tiles).
    double ra[16], rb[16];
    double ec = 0.0, ve = 0.0;                    // edge prefetch registers
    #pragma unroll
    for (int w = 0; w < 16; ++w) {
        int idx = w * 64 + lane; int cc = idx >> 5, mm = idx & 31;
        ra[w] = gload_cc(&C[(aJ + cc) * NN + aJ + mm]);
    }
    #pragma unroll
    for (int u = 0; u < 16; ++u) {
        int kk = h * 16 + u;
        rb[u] = gload_cc(&R[(aI + r) * NN + aI + kk]);
    }
    if (nk == 0) {
        if (lane < 33) ec = gload_cc(&R[(aI + lane) * NN + (aJ - 1)]);
        if (lane < 32) ve = gload_cc(&R[(aI + 32) * NN + aJ + lane]);
    }
    for (int w = 0; w < 16; ++w) {
        int idx = w * 64 + lane; int rr = idx >> 5, cc = idx & 31;
        Sld[rr][cc] = S[(aI + rr) * NN + aJ + cc];
    }
    for (int idx = lane; idx < 32 * 33; idx += 64)
        ((double*)Vtc)[idx] = 0.0;
    VWAIT0;
    #pragma unroll
    for (int w = 0; w < 16; ++w) {
        int idx = w * 64 + lane; int cc = idx >> 5, mm = idx & 31;
        DJJc[cc][mm] = ra[w];
    }
    if (lane < 32) DJJc[lane][32] = 0.0;
    if (nk == 0) {
        if (lane < 33) edgeCol[lane] = ec;
        if (lane < 32) Vtc[lane][32] = ve;
    }

    double aslice[16];
    #pragma unroll
    for (int u = 0; u < 16; ++u) {
        int kk = h * 16 + u;
        aslice[u] = (kk >= r) ? rb[u] : -1.0e30;
    }

    // ---- phaseA: middle-out k-tile order, readiness-aligned PAIRS ----
    // The FINAL proc always covers t=I+1 and t=J-1 (verified over the
    // pend/pair driver), so its waitflags imply (I,J-1) and (I+1,J) done:
    // edge loads are prefetched there, hiding their RTT under the kk-loops.
    double P[16];
    #pragma unroll
    for (int x = 0; x < 16; ++x) P[x] = 0.0;
    const int rg = lane >> 3, cg = lane & 7;
    const int r4 = rg * 4, c4 = cg * 4;

    auto kkloop = [&]() {
        for (int kk = 0; kk < 32; ++kk) {
            double2 av0 = *(const double2*)&Ast[kk][r4];
            double2 av1 = *(const double2*)&Ast[kk][r4 + 2];
            double2 bv0 = *(const double2*)&Bst[kk][c4];
            double2 bv1 = *(const double2*)&Bst[kk][c4 + 2];
            P[0]  = fmax(P[0],  av0.x + bv0.x); P[1]  = fmax(P[1],  av0.x + bv0.y);
            P[2]  = fmax(P[2],  av0.x + bv1.x); P[3]  = fmax(P[3],  av0.x + bv1.y);
            P[4]  = fmax(P[4],  av0.y + bv0.x); P[5]  = fmax(P[5],  av0.y + bv0.y);
            P[6]  = fmax(P[6],  av0.y + bv1.x); P[7]  = fmax(P[7],  av0.y + bv1.y);
            P[8]  = fmax(P[8],  av1.x + bv0.x); P[9]  = fmax(P[9],  av1.x + bv0.y);
            P[10] = fmax(P[10], av1.x + bv1.x); P[11] = fmax(P[11], av1.x + bv1.y);
            P[12] = fmax(P[12], av1.y + bv0.x); P[13] = fmax(P[13], av1.y + bv0.y);
            P[14] = fmax(P[14], av1.y + bv1.x); P[15] = fmax(P[15], av1.y + bv1.y);
        }
    };
    auto proc = [&](int t1, int t2, bool last) {
        if (t2 >= 0) waitflag4(flags, I, t1, t1, J, I, t2, t2, J);
        else         waitflag2(flags, I, t1, t1, J);
        if (last) {                                 // edge prefetch (RTT hidden)
            if (lane < 33) ec = gload_cc(&R[(aI + lane) * NN + (aJ - 1)]);
            if (lane < 32) ve = gload_cc(&R[(aI + 32) * NN + aJ + lane]);
        }
        int k1 = t1 * BT;
        #pragma unroll
        for (int w = 0; w < 16; ++w) {
            int idx = w * 64 + lane; int rr = idx >> 5, kk = idx & 31;
            ra[w] = gload_cc(&R[(aI + rr) * NN + k1 + kk]);
            rb[w] = gload_cc(&C[(aJ + rr) * NN + k1 + 1 + kk]);
        }
        VWAIT0;
        #pragma unroll
        for (int w = 0; w < 16; ++w) {
            int idx = w * 64 + lane; int rr = idx >> 5, kk = idx & 31;
            Ast[kk][rr] = ra[w];
            Bst[kk][rr] = rb[w];
        }
        if (last) {
            if (lane < 33) edgeCol[lane] = ec;
            if (lane < 32) Vtc[lane][32] = ve;
        }
        if (t2 >= 0) {
            int k2 = t2 * BT;
            #pragma unroll
            for (int w = 0; w < 16; ++w) {
                int idx = w * 64 + lane; int rr = idx >> 5, kk = idx & 31;
                ra[w] = gload_cc(&R[(aI + rr) * NN + k2 + kk]);
                rb[w] = gload_cc(&C[(aJ + rr) * NN + k2 + 1 + kk]);
            }
        }
        kkloop();
        if (t2 >= 0) {
            VWAIT0;
            #pragma unroll
            for (int w = 0; w < 16; ++w) {
                int idx = w * 64 + lane; int rr = idx >> 5, kk = idx & 31;
                Ast[kk][rr] = ra[w];
                Bst[kk][rr] = rb[w];
            }
            kkloop();
        }
    };

    {
        int tl = (I + J) >> 1, tr = ((I + J) >> 1) + 1;
        int pend = -1;
        for (int q = 0; q < nk; ++q) {
            int t;
            if ((q & 1) == 0) { if (tl >= I + 1) t = tl--; else t = tr++; }
            else              { if (tr <= J - 1) t = tr++; else t = tl--; }
            if (pend < 0) { pend = t; continue; }
            int rp = (pend - I > J - pend) ? pend - I : J - pend;
            int rt = (t - I > J - t) ? t - I : J - t;
            if (rp == rt) { proc(pend, t, q == nk - 1); pend = -1; }
            else          { proc(pend, -1, false); pend = t; }
        }
        if (pend >= 0) proc(pend, -1, true);
    }

    if (nk > 0) {
        #pragma unroll
        for (int x = 0; x < 4; ++x)
            #pragma unroll
            for (int y = 0; y < 4; ++y)
                Pld[r4 + x][c4 + y] = P[x * 4 + y];
    } else {
        for (int idx = lane; idx < 32 * 33; idx += 64)
            ((double*)Pld)[idx] = 0.0;
    }

    // ---- phaseB: 63 anti-diagonal micro-steps, barrier-free ----
    double vrow[16];
    #pragma unroll
    for (int u = 0; u < 16; ++u) vrow[u] = 0.0;

    for (int s = 0; s < 63; ++s) {
        int c = r + s - 31;
        bool act = ((unsigned)c < 32u);
        double acc = -1.0e30;
        if (act) {
            double t0 = -1.0e30, t1 = -1.0e30, t2 = -1.0e30, t3 = -1.0e30;
            #pragma unroll
            for (int u = 0; u < 16; u += 4) {
                int k0 = h * 16 + u;
                t0 = fmax(t0, aslice[u]     + Vtc[c][k0 + 1]);
                t1 = fmax(t1, aslice[u + 1] + Vtc[c][k0 + 2]);
                t2 = fmax(t2, aslice[u + 2] + Vtc[c][k0 + 3]);
                t3 = fmax(t3, aslice[u + 3] + Vtc[c][k0 + 4]);
            }
            double q0 = -1.0e30, q1 = -1.0e30, q2 = -1.0e30, q3 = -1.0e30;
            #pragma unroll
            for (int u = 0; u < 16; u += 4) {
                int m0 = h * 16 + u + 1;
                q0 = fmax(q0, vrow[u]     + DJJc[c][m0]);
                q1 = fmax(q1, vrow[u + 1] + DJJc[c][m0 + 1]);
                q2 = fmax(q2, vrow[u + 2] + DJJc[c][m0 + 2]);
                q3 = fmax(q3, vrow[u + 3] + DJJc[c][m0 + 3]);
            }
            acc = fmax(fmax(fmax(t0, t1), fmax(t2, t3)),
                       fmax(fmax(q0, q1), fmax(q2, q3)));
        }
        acc = fmax(acc, __shfl_xor(acc, 1));
        if (act) {
            double best = acc;
            best = fmax(best, edgeCol[r] + DJJc[c][0]);      // k = aJ-1
            best = fmax(best, Pld[r][c]);                    // external k-tiles
            double pv = (c > 0) ? Vtc[c - 1][r + 1] : edgeCol[r + 1];
            best = fmax(best, pv + (double)Sld[r][c]);       // pair
            if (h == 0) Vtc[c][r] = best;
            #pragma unroll
            for (int u = 0; u < 16; ++u)
                if (h * 16 + u == c) vrow[u] = best;
        }
    }

    for (int w = 0; w < 16; ++w) {
        int idx = w * 64 + lane; int rr = idx >> 5, cc = idx & 31;
        gstore_cc(&R[(aI + rr) * NN + aJ + cc], Vtc[cc][rr]);
    }
    for (int w = 0; w < 16; ++w) {
        int idx = w * 64 + lane; int cc = idx >> 5, rr = idx & 31;
        gstore_cc(&C[(aJ + cc) * NN + aI + rr], Vtc[cc][rr]);
    }
    VWAIT0;                                       // data at coherence point
    if (lane == 0) gstore_flag(&flags[(I * TT + J) << 4], 1);
}

// ---------------------------------------------------------------------------
// Traceback, software-pipelined: successor operands are loaded BEFORE the
// branch decision, hiding one L2 latency per event. Semantics unchanged.
// ---------------------------------------------------------------------------
__global__ __launch_bounds__(256) void traceback_kernel(const double* __restrict__ R,
                                                        const double* __restrict__ C,
                                                        const float* __restrict__ S,
                                                        float* __restrict__ out) {
    __shared__ int stk_i[2048];
    __shared__ int stk_j[2048];
    __shared__ double stk_v[2048];
    __shared__ int sh_top, sh_ii, sh_jj, sh_cmd;
    __shared__ double sred_v[4];
    __shared__ int sred_k[4];
    const double eps = 1e-9;
    if (threadIdx.x == 0) {
        sh_top = 1; stk_i[0] = 0; stk_j[0] = NN - 1; stk_v[0] = R[NN - 1];
    }
    __syncthreads();
    while (true) {
        if (threadIdx.x == 0) {
            int cmd = -1, top = sh_top;
            int i = 0, j = 0; double v = 0.0, a = 0.0, b2 = 0.0; float sv = 0.0f;
            bool have = false;
            while (true) {
                if (!have) {
                    if (top == 0) { cmd = -1; break; }
                    i = stk_i[--top]; j = stk_j[top]; v = stk_v[top];
                    if (j <= i || v <= eps) continue;
                    a  = R[(i + 1) * NN + j];
                    sv = S[i * NN + j];
                    b2 = R[(i + 1) * NN + j - 1];
                    have = true;
                    continue;
                }
                int ip = (i + 2 <= NN - 1) ? i + 2 : NN - 1;    // clamp (unused if OOB)
                int jl = (j - 2 >= 0) ? j - 2 : 0;
                double ar = R[ip * NN + j];
                double br = R[ip * NN + j - 1];
                double bl = R[ip * NN + jl];
                float  sr = S[(i + 1) * NN + j];
                float  sl = S[(i + 1) * NN + j - 1];
                if (a >= v - eps) {
                    ++i; v = a; a = ar; sv = sr; b2 = br;
                    if (j <= i || v <= eps) have = false;
                    continue;
                }
                if (sv > 0.0f && b2 + (double)sv >= v - eps) {
                    out[i * NN + j] = sv; out[j * NN + i] = sv;
                    ++i; --j; v = b2; a = br; sv = sl; b2 = bl;
                    if (j <= i || v <= eps) have = false;
                    continue;
                }
                sh_ii = i; sh_jj = j; cmd = 0; break;
            }
            sh_top = top; sh_cmd = cmd;
        }
        __syncthreads();
        if (sh_cmd < 0) break;
        int i = sh_ii, j = sh_jj;
        double bv = -1.0; int bk = 0x7fffffff;
        for (int k = i + threadIdx.x; k < j; k += 256) {
            double tv = R[i * NN + k] + C[j * NN + k + 1];
            if (tv > bv) { bv = tv; bk = k; }
        }
        for (int off = 32; off; off >>= 1) {
            double ov = __shfl_down(bv, off);
            int   ok = __shfl_down(bk, off);
            if (ov > bv || (ov == bv && ok < bk)) { bv = ov; bk = ok; }
        }
        if ((threadIdx.x & 63) == 0) { sred_v[threadIdx.x >> 6] = bv; sred_k[threadIdx.x >> 6] = bk; }
        __syncthreads();
        if (threadIdx.x == 0) {
            double fv = sred_v[0]; int fk = sred_k[0];
            for (int w = 1; w < 4; ++w)
                if (sred_v[w] > fv || (sred_v[w] == fv && sred_k[w] < fk)) { fv = sred_v[w]; fk = sred_k[w]; }
            int top = sh_top;
            stk_i[top] = sh_ii;  stk_j[top] = fk;    stk_v[top] = R[sh_ii * NN + fk];      ++top;
            stk_i[top] = fk + 1; stk_j[top] = sh_jj; stk_v[top] = C[sh_jj * NN + fk + 1];  ++top;
            sh_top = top;
        }
        __syncthreads();
    }
}

// ---------------------------------------------------------------------------
extern "C" void kernel_launch(void* const* d_in, const int* in_sizes, int n_in,
                              void* d_out, int out_size, void* d_ws, size_t ws_size,
                              hipStream_t stream) {
    const float* con  = (const float*)d_in[0];
    const float* feat = (const float*)d_in[1];
    float* out = (float*)d_out;

    char* ws = (char*)d_ws;
    double* R      = (double*)(ws);
    double* C      = (double*)(ws + (size_t)8  * 1024 * 1024);
    float*  S      = (float*) (ws + (size_t)16 * 1024 * 1024);
    int*    primes = (int*)   (ws + (size_t)20 * 1024 * 1024);
    int*    flags  = (int*)   (ws + (size_t)20 * 1024 * 1024 + 8192);

    primes_kernel<<<(NN + 255) / 256, 256, 0, stream>>>(feat, primes);
    prep_kernel<<<(NN * NN) / 256, 256, 0, stream>>>(con, primes, S, R, C, out, flags);
    nuss_tiles_kernel<<<NTILES, 64, 0, stream>>>(R, C, S, flags);
    traceback_kernel<<<1, 256, 0, stream>>>(R, C, S, out);
}

// Round 5
// 1806.832 us; speedup vs baseline: 1.1626x; 1.1622x over previous
//
#include <hip/hip_runtime.h>

#define NN 1024
#define BT 32
#define TT 32
#define NTILES ((TT * (TT + 1)) / 2)   // 528

// ---------------------------------------------------------------------------
// Fence-free cross-XCD protocol (batched sc0sc1 MALL ops, active-spin polls).
// Round-5 change: phaseB software-pipelined (prefetch + shuffle chain) so the
// 63-step in-tile wavefront no longer stalls on LDS latency every step.
// ---------------------------------------------------------------------------
__device__ __forceinline__ double gload_cc(const double* p) {
    double v;
    asm volatile("global_load_dwordx2 %0, %1, off sc0 sc1" : "=v"(v) : "v"(p));
    return v;
}
__device__ __forceinline__ void gstore_cc(double* p, double v) {
    asm volatile("global_store_dwordx2 %0, %1, off sc0 sc1" :: "v"(p), "v"(v));
}
__device__ __forceinline__ void gstore_flag(int* p, int v) {
    asm volatile("global_store_dword %0, %1, off sc0 sc1" :: "v"(p), "v"(v));
}
#define VWAIT0 asm volatile("s_waitcnt vmcnt(0)" ::: "memory")

__device__ __forceinline__ void waitflag2(const int* f, int a0, int b0, int a1, int b1) {
    const int* p0 = &f[(a0 * TT + b0) << 4];
    const int* p1 = &f[(a1 * TT + b1) << 4];
    double x = (double)(unsigned long long)p0;
    while (true) {
        int v0, v1;
        asm volatile("global_load_dword %0, %2, off sc0 sc1\n\t"
                     "global_load_dword %1, %3, off sc0 sc1\n\t"
                     "s_waitcnt vmcnt(0)"
                     : "=&v"(v0), "=&v"(v1)
                     : "v"(p0), "v"(p1));
        if (v0 & v1) break;
        #pragma unroll
        for (int i = 0; i < 24; ++i) x = fma(x, 1.0000000001, 1.0e-300);
    }
    asm volatile("" :: "v"(x));
    asm volatile("" ::: "memory");
}
__device__ __forceinline__ void waitflag4(const int* f, int a0, int b0, int a1, int b1,
                                          int a2, int b2, int a3, int b3) {
    const int* p0 = &f[(a0 * TT + b0) << 4];
    const int* p1 = &f[(a1 * TT + b1) << 4];
    const int* p2 = &f[(a2 * TT + b2) << 4];
    const int* p3 = &f[(a3 * TT + b3) << 4];
    double x = (double)(unsigned long long)p0;
    while (true) {
        int v0, v1, v2, v3;
        asm volatile("global_load_dword %0, %4, off sc0 sc1\n\t"
                     "global_load_dword %1, %5, off sc0 sc1\n\t"
                     "global_load_dword %2, %6, off sc0 sc1\n\t"
                     "global_load_dword %3, %7, off sc0 sc1\n\t"
                     "s_waitcnt vmcnt(0)"
                     : "=&v"(v0), "=&v"(v1), "=&v"(v2), "=&v"(v3)
                     : "v"(p0), "v"(p1), "v"(p2), "v"(p3));
        if (v0 & v1 & v2 & v3) break;
        #pragma unroll
        for (int i = 0; i < 24; ++i) x = fma(x, 1.0000000001, 1.0e-300);
    }
    asm volatile("" :: "v"(x));
    asm volatile("" ::: "memory");
}

// ---------------------------------------------------------------------------
__global__ void primes_kernel(const float* __restrict__ feat, int* __restrict__ primes) {
    int i = blockIdx.x * blockDim.x + threadIdx.x;
    if (i < NN) {
        float best = feat[i * NN];
        int arg = 0;
        for (int ch = 1; ch < 4; ++ch) {
            float v = feat[ch * NN * NN + i * NN];
            if (v > best) { best = v; arg = ch; }
        }
        const int P[4] = {2, 3, 5, 7};
        primes[i] = P[arg];
    }
}

__global__ void prep_kernel(const float* __restrict__ con, const int* __restrict__ primes,
                            float* __restrict__ S, double* __restrict__ R,
                            double* __restrict__ C, float* __restrict__ out,
                            int* __restrict__ flags) {
    int idx = blockIdx.x * blockDim.x + threadIdx.x;
    int i = idx >> 10;
    int j = idx & (NN - 1);
    float c = (con[idx] + con[j * NN + i]) * 0.5f;
    int prod = primes[i] * primes[j];
    bool canon = (prod == 14) | (prod == 15) | (prod == 35);
    int d = i - j; if (d < 0) d = -d;
    S[idx] = (canon && d >= 4) ? c : 0.0f;
    R[idx] = 0.0;
    C[idx] = 0.0;
    out[idx] = 0.0f;
    if (idx < TT * TT * 16) flags[idx] = 0;
}

// ---------------------------------------------------------------------------
// Dataflow DP, one wave per 32x32 tile. Exactness: every candidate is one
// fp64 add of stored values; extra candidates are dominated (-1e30+x<0<=dp,
// stale-0 + 0 = 0 <= dp); fmax is exact/associative => bitwise == numpy.
// phaseB pipelining exactness: kk==r term == 0 + V(r+1,c) (diag of V is 0),
// delivered via shuffle from lane r+1 (computed at step s-1); prefetched LDS
// reads only consume values written >= 2 steps earlier (in-order wave DS);
// fresher slots are masked to -1e30 by the kk>r guard.
// ---------------------------------------------------------------------------
__global__ __launch_bounds__(64) void nuss_tiles_kernel(double* __restrict__ R,
                                                        double* __restrict__ C,
                                                        const float* __restrict__ S,
                                                        int* __restrict__ flags) {
    __shared__ double DJJc[32][33];                         // DJJc[c][m]=V(aJ+m,aJ+c); [32]=0
    __shared__ double Vtc[32][33];                          // Vtc[c][r]=V(aI+r,aJ+c); [32]=edge
    __shared__ __attribute__((aligned(16))) double Ast[32][34]; // Ast[kk][r]=V(aI+r,kt0+kk)
    __shared__ __attribute__((aligned(16))) double Bst[32][34]; // Bst[kk][c]=V(kt0+kk+1,aJ+c)
    __shared__ double Pld[32][33];
    __shared__ float  Sld[32][32];
    __shared__ double edgeCol[33];                          // V(aI+rr, aJ-1)

    int b = blockIdx.x, dd = 0;
    while (b >= TT - dd) { b -= TT - dd; ++dd; }
    const int I = b, J = b + dd;
    const int aI = I * BT, aJ = J * BT;
    const int lane = threadIdx.x;
    const int r = lane >> 1;
    const int h = lane & 1;

    if (dd == 0) {
        // ---------------- diagonal tile (unchanged) ----------------
        for (int w = 0; w < 16; ++w) {
            int idx = w * 64 + lane; int rr = idx >> 5, cc = idx & 31;
            Sld[rr][cc] = S[(aI + rr) * NN + aI + cc];
        }
        for (int idx = lane; idx < 32 * 33; idx += 64)
            ((double*)Vtc)[idx] = 0.0;
        double vrow[16];
        #pragma unroll
        for (int u = 0; u < 16; ++u) vrow[u] = 0.0;

        for (int s = 1; s <= 31; ++s) {
            int c = r + s;
            bool act = (c <= 31);
            double acc = 0.0;
            if (act) {
                double t0 = 0.0, t1 = 0.0, t2 = 0.0, t3 = 0.0;
                #pragma unroll
                for (int u = 0; u < 16; u += 4) {
                    int k0 = h * 16 + u;
                    t0 = fmax(t0, vrow[u]     + Vtc[c][k0 + 1]);
                    t1 = fmax(t1, vrow[u + 1] + Vtc[c][k0 + 2]);
                    t2 = fmax(t2, vrow[u + 2] + Vtc[c][k0 + 3]);
                    t3 = fmax(t3, vrow[u + 3] + Vtc[c][k0 + 4]);
                }
                acc = fmax(fmax(t0, t1), fmax(t2, t3));
            }
            acc = fmax(acc, __shfl_xor(acc, 1));
            if (act) {
                double best = fmax(acc, Vtc[c - 1][r + 1] + (double)Sld[r][c]);
                if (h == 0) Vtc[c][r] = best;
                #pragma unroll
                for (int u = 0; u < 16; ++u)
                    if (h * 16 + u == c) vrow[u] = best;
            }
        }
        for (int w = 0; w < 16; ++w) {
            int idx = w * 64 + lane; int rr = idx >> 5, cc = idx & 31;
            gstore_cc(&R[(aI + rr) * NN + aI + cc], Vtc[cc][rr]);
        }
        for (int w = 0; w < 16; ++w) {
            int idx = w * 64 + lane; int cc = idx >> 5, rr = idx & 31;
            gstore_cc(&C[(aI + cc) * NN + aI + rr], Vtc[cc][rr]);
        }
        VWAIT0;
        if (lane == 0) gstore_flag(&flags[(I * TT + I) << 4], 1);
        return;
    }

    // ---------------- off-diagonal tile ----------------
    const int nk = dd - 1;
    waitflag2(flags, I, I, J, J);

    double ra[16], rb[16];
    double ec = 0.0, ve = 0.0;
    #pragma unroll
    for (int w = 0; w < 16; ++w) {
        int idx = w * 64 + lane; int cc = idx >> 5, mm = idx & 31;
        ra[w] = gload_cc(&C[(aJ + cc) * NN + aJ + mm]);
    }
    #pragma unroll
    for (int u = 0; u < 16; ++u) {
        int kk = h * 16 + u;
        rb[u] = gload_cc(&R[(aI + r) * NN + aI + kk]);
    }
    if (nk == 0) {
        if (lane < 33) ec = gload_cc(&R[(aI + lane) * NN + (aJ - 1)]);
        if (lane < 32) ve = gload_cc(&R[(aI + 32) * NN + aJ + lane]);
    }
    for (int w = 0; w < 16; ++w) {
        int idx = w * 64 + lane; int rr = idx >> 5, cc = idx & 31;
        Sld[rr][cc] = S[(aI + rr) * NN + aJ + cc];
    }
    for (int idx = lane; idx < 32 * 33; idx += 64)
        ((double*)Vtc)[idx] = 0.0;
    VWAIT0;
    #pragma unroll
    for (int w = 0; w < 16; ++w) {
        int idx = w * 64 + lane; int cc = idx >> 5, mm = idx & 31;
        DJJc[cc][mm] = ra[w];
    }
    if (lane < 32) DJJc[lane][32] = 0.0;
    if (nk == 0) {
        if (lane < 33) edgeCol[lane] = ec;
        if (lane < 32) Vtc[lane][32] = ve;
    }

    // aslice guard: kk > r. The kk==r term (== 0 + V(r+1,c)) moves to the
    // shuffle path in phaseB.
    double aslice[16];
    #pragma unroll
    for (int u = 0; u < 16; ++u) {
        int kk = h * 16 + u;
        aslice[u] = (kk > r) ? rb[u] : -1.0e30;
    }

    // ---- phaseA: middle-out k-tile order, readiness-aligned PAIRS ----
    double P[16];
    #pragma unroll
    for (int x = 0; x < 16; ++x) P[x] = 0.0;
    const int rg = lane >> 3, cg = lane & 7;
    const int r4 = rg * 4, c4 = cg * 4;

    auto kkloop = [&]() {
        for (int kk = 0; kk < 32; ++kk) {
            double2 av0 = *(const double2*)&Ast[kk][r4];
            double2 av1 = *(const double2*)&Ast[kk][r4 + 2];
            double2 bv0 = *(const double2*)&Bst[kk][c4];
            double2 bv1 = *(const double2*)&Bst[kk][c4 + 2];
            P[0]  = fmax(P[0],  av0.x + bv0.x); P[1]  = fmax(P[1],  av0.x + bv0.y);
            P[2]  = fmax(P[2],  av0.x + bv1.x); P[3]  = fmax(P[3],  av0.x + bv1.y);
            P[4]  = fmax(P[4],  av0.y + bv0.x); P[5]  = fmax(P[5],  av0.y + bv0.y);
            P[6]  = fmax(P[6],  av0.y + bv1.x); P[7]  = fmax(P[7],  av0.y + bv1.y);
            P[8]  = fmax(P[8],  av1.x + bv0.x); P[9]  = fmax(P[9],  av1.x + bv0.y);
            P[10] = fmax(P[10], av1.x + bv1.x); P[11] = fmax(P[11], av1.x + bv1.y);
            P[12] = fmax(P[12], av1.y + bv0.x); P[13] = fmax(P[13], av1.y + bv0.y);
            P[14] = fmax(P[14], av1.y + bv1.x); P[15] = fmax(P[15], av1.y + bv1.y);
        }
    };
    auto proc = [&](int t1, int t2, bool last) {
        if (t2 >= 0) waitflag4(flags, I, t1, t1, J, I, t2, t2, J);
        else         waitflag2(flags, I, t1, t1, J);
        if (last) {
            if (lane < 33) ec = gload_cc(&R[(aI + lane) * NN + (aJ - 1)]);
            if (lane < 32) ve = gload_cc(&R[(aI + 32) * NN + aJ + lane]);
        }
        int k1 = t1 * BT;
        #pragma unroll
        for (int w = 0; w < 16; ++w) {
            int idx = w * 64 + lane; int rr = idx >> 5, kk = idx & 31;
            ra[w] = gload_cc(&R[(aI + rr) * NN + k1 + kk]);
            rb[w] = gload_cc(&C[(aJ + rr) * NN + k1 + 1 + kk]);
        }
        VWAIT0;
        #pragma unroll
        for (int w = 0; w < 16; ++w) {
            int idx = w * 64 + lane; int rr = idx >> 5, kk = idx & 31;
            Ast[kk][rr] = ra[w];
            Bst[kk][rr] = rb[w];
        }
        if (last) {
            if (lane < 33) edgeCol[lane] = ec;
            if (lane < 32) Vtc[lane][32] = ve;
        }
        if (t2 >= 0) {
            int k2 = t2 * BT;
            #pragma unroll
            for (int w = 0; w < 16; ++w) {
                int idx = w * 64 + lane; int rr = idx >> 5, kk = idx & 31;
                ra[w] = gload_cc(&R[(aI + rr) * NN + k2 + kk]);
                rb[w] = gload_cc(&C[(aJ + rr) * NN + k2 + 1 + kk]);
            }
        }
        kkloop();
        if (t2 >= 0) {
            VWAIT0;
            #pragma unroll
            for (int w = 0; w < 16; ++w) {
                int idx = w * 64 + lane; int rr = idx >> 5, kk = idx & 31;
                Ast[kk][rr] = ra[w];
                Bst[kk][rr] = rb[w];
            }
            kkloop();
        }
    };

    {
        int tl = (I + J) >> 1, tr = ((I + J) >> 1) + 1;
        int pend = -1;
        for (int q = 0; q < nk; ++q) {
            int t;
            if ((q & 1) == 0) { if (tl >= I + 1) t = tl--; else t = tr++; }
            else              { if (tr <= J - 1) t = tr++; else t = tl--; }
            if (pend < 0) { pend = t; continue; }
            int rp = (pend - I > J - pend) ? pend - I : J - pend;
            int rt = (t - I > J - t) ? t - I : J - t;
            if (rp == rt) { proc(pend, t, q == nk - 1); pend = -1; }
            else          { proc(pend, -1, false); pend = t; }
        }
        if (pend >= 0) proc(pend, -1, true);
    }

    if (nk > 0) {
        #pragma unroll
        for (int x = 0; x < 4; ++x)
            #pragma unroll
            for (int y = 0; y < 4; ++y)
                Pld[r4 + x][c4 + y] = P[x * 4 + y];
    } else {
        for (int idx = lane; idx < 32 * 33; idx += 64)
            ((double*)Pld)[idx] = 0.0;
    }

    // ---- phaseB: 63 anti-diagonal steps, software-pipelined ----
    double vrow[16];
    #pragma unroll
    for (int u = 0; u < 16; ++u) vrow[u] = 0.0;

    double ecr = edgeCol[r];        // step-invariant per lane
    double ecp = edgeCol[r + 1];

    double tvA[16], qvA[16], tvB[16], qvB[16];
    double p1 = 0.0, shc = 0.0, shp = 0.0, erc = 0.0, erp = 0.0;

#define PREFB(TV, QV, S)                                              \
    { int cc_ = (r + (S) - 31); cc_ = cc_ < 0 ? 0 : (cc_ > 31 ? 31 : cc_); \
      _Pragma("unroll")                                               \
      for (int u = 0; u < 16; ++u) {                                  \
          TV[u] = Vtc[cc_][h * 16 + u + 1];                           \
          QV[u] = DJJc[cc_][h * 16 + u + 1];                          \
      } }

#define STEPB(TV, QV, S)                                              \
    { int c_ = r + (S) - 31;                                          \
      bool act_ = ((unsigned)c_ < 32u);                               \
      int cc_ = c_ < 0 ? 0 : (c_ > 31 ? 31 : c_);                     \
      double er_  = Vtc[cc_][32];                                     \
      double dj0_ = DJJc[cc_][0];                                     \
      double pld_ = Pld[r][cc_];                                      \
      float  sld_ = Sld[r][cc_];                                      \
      shp = shc; erp = erc; erc = er_;                                \
      shc = __shfl_down(p1, 2);                                       \
      double acc_ = -1.0e30;                                          \
      if (act_) {                                                     \
          double t0_ = -1.0e30, t1_ = -1.0e30, t2_ = -1.0e30, t3_ = -1.0e30; \
          _Pragma("unroll")                                           \
          for (int u = 0; u < 16; u += 4) {                           \
              t0_ = fmax(t0_, aslice[u]     + TV[u]);                 \
              t1_ = fmax(t1_, aslice[u + 1] + TV[u + 1]);             \
              t2_ = fmax(t2_, aslice[u + 2] + TV[u + 2]);             \
              t3_ = fmax(t3_, aslice[u + 3] + TV[u + 3]);             \
          }                                                           \
          _Pragma("unroll")                                           \
          for (int u = 0; u < 16; u += 4) {                           \
              t0_ = fmax(t0_, vrow[u]     + QV[u]);                   \
              t1_ = fmax(t1_, vrow[u + 1] + QV[u + 1]);               \
              t2_ = fmax(t2_, vrow[u + 2] + QV[u + 2]);               \
              t3_ = fmax(t3_, vrow[u + 3] + QV[u + 3]);               \
          }                                                           \
          acc_ = fmax(fmax(t0_, t1_), fmax(t2_, t3_));                \
      }                                                               \
      acc_ = fmax(acc_, __shfl_xor(acc_, 1));                         \
      if (act_) {                                                     \
          double best_ = acc_;                                        \
          best_ = fmax(best_, (r == 31) ? erc : shc);                 \
          best_ = fmax(best_, ecr + dj0_);                            \
          best_ = fmax(best_, pld_);                                  \
          double pv_ = (c_ == 0) ? ecp : ((r == 31) ? erp : shp);     \
          best_ = fmax(best_, pv_ + (double)sld_);                    \
          if (h == 0) Vtc[c_][r] = best_;                             \
          _Pragma("unroll")                                           \
          for (int u = 0; u < 16; ++u)                                \
              if (h * 16 + u == c_) vrow[u] = best_;                  \
          p1 = best_;                                                 \
      } }

    PREFB(tvA, qvA, 0)
    for (int s2 = 0; s2 < 64; s2 += 2) {
        PREFB(tvB, qvB, s2 + 1)
        STEPB(tvA, qvA, s2)
        PREFB(tvA, qvA, s2 + 2)
        STEPB(tvB, qvB, s2 + 1)
    }
#undef PREFB
#undef STEPB

    for (int w = 0; w < 16; ++w) {
        int idx = w * 64 + lane; int rr = idx >> 5, cc = idx & 31;
        gstore_cc(&R[(aI + rr) * NN + aJ + cc], Vtc[cc][rr]);
    }
    for (int w = 0; w < 16; ++w) {
        int idx = w * 64 + lane; int cc = idx >> 5, rr = idx & 31;
        gstore_cc(&C[(aJ + cc) * NN + aI + rr], Vtc[cc][rr]);
    }
    VWAIT0;
    if (lane == 0) gstore_flag(&flags[(I * TT + J) << 4], 1);
}

// ---------------------------------------------------------------------------
// Traceback, software-pipelined (unchanged).
// ---------------------------------------------------------------------------
__global__ __launch_bounds__(256) void traceback_kernel(const double* __restrict__ R,
                                                        const double* __restrict__ C,
                                                        const float* __restrict__ S,
                                                        float* __restrict__ out) {
    __shared__ int stk_i[2048];
    __shared__ int stk_j[2048];
    __shared__ double stk_v[2048];
    __shared__ int sh_top, sh_ii, sh_jj, sh_cmd;
    __shared__ double sred_v[4];
    __shared__ int sred_k[4];
    const double eps = 1e-9;
    if (threadIdx.x == 0) {
        sh_top = 1; stk_i[0] = 0; stk_j[0] = NN - 1; stk_v[0] = R[NN - 1];
    }
    __syncthreads();
    while (true) {
        if (threadIdx.x == 0) {
            int cmd = -1, top = sh_top;
            int i = 0, j = 0; double v = 0.0, a = 0.0, b2 = 0.0; float sv = 0.0f;
            bool have = false;
            while (true) {
                if (!have) {
                    if (top == 0) { cmd = -1; break; }
                    i = stk_i[--top]; j = stk_j[top]; v = stk_v[top];
                    if (j <= i || v <= eps) continue;
                    a  = R[(i + 1) * NN + j];
                    sv = S[i * NN + j];
                    b2 = R[(i + 1) * NN + j - 1];
                    have = true;
                    continue;
                }
                int ip = (i + 2 <= NN - 1) ? i + 2 : NN - 1;
                int jl = (j - 2 >= 0) ? j - 2 : 0;
                double ar = R[ip * NN + j];
                double br = R[ip * NN + j - 1];
                double bl = R[ip * NN + jl];
                float  sr = S[(i + 1) * NN + j];
                float  sl = S[(i + 1) * NN + j - 1];
                if (a >= v - eps) {
                    ++i; v = a; a = ar; sv = sr; b2 = br;
                    if (j <= i || v <= eps) have = false;
                    continue;
                }
                if (sv > 0.0f && b2 + (double)sv >= v - eps) {
                    out[i * NN + j] = sv; out[j * NN + i] = sv;
                    ++i; --j; v = b2; a = br; sv = sl; b2 = bl;
                    if (j <= i || v <= eps) have = false;
                    continue;
                }
                sh_ii = i; sh_jj = j; cmd = 0; break;
            }
            sh_top = top; sh_cmd = cmd;
        }
        __syncthreads();
        if (sh_cmd < 0) break;
        int i = sh_ii, j = sh_jj;
        double bv = -1.0; int bk = 0x7fffffff;
        for (int k = i + threadIdx.x; k < j; k += 256) {
            double tv = R[i * NN + k] + C[j * NN + k + 1];
            if (tv > bv) { bv = tv; bk = k; }
        }
        for (int off = 32; off; off >>= 1) {
            double ov = __shfl_down(bv, off);
            int   ok = __shfl_down(bk, off);
            if (ov > bv || (ov == bv && ok < bk)) { bv = ov; bk = ok; }
        }
        if ((threadIdx.x & 63) == 0) { sred_v[threadIdx.x >> 6] = bv; sred_k[threadIdx.x >> 6] = bk; }
        __syncthreads();
        if (threadIdx.x == 0) {
            double fv = sred_v[0]; int fk = sred_k[0];
            for (int w = 1; w < 4; ++w)
                if (sred_v[w] > fv || (sred_v[w] == fv && sred_k[w] < fk)) { fv = sred_v[w]; fk = sred_k[w]; }
            int top = sh_top;
            stk_i[top] = sh_ii;  stk_j[top] = fk;    stk_v[top] = R[sh_ii * NN + fk];      ++top;
            stk_i[top] = fk + 1; stk_j[top] = sh_jj; stk_v[top] = C[sh_jj * NN + fk + 1];  ++top;
            sh_top = top;
        }
        __syncthreads();
    }
}

// ---------------------------------------------------------------------------
extern "C" void kernel_launch(void* const* d_in, const int* in_sizes, int n_in,
                              void* d_out, int out_size, void* d_ws, size_t ws_size,
                              hipStream_t stream) {
    const float* con  = (const float*)d_in[0];
    const float* feat = (const float*)d_in[1];
    float* out = (float*)d_out;

    char* ws = (char*)d_ws;
    double* R      = (double*)(ws);
    double* C      = (double*)(ws + (size_t)8  * 1024 * 1024);
    float*  S      = (float*) (ws + (size_t)16 * 1024 * 1024);
    int*    primes = (int*)   (ws + (size_t)20 * 1024 * 1024);
    int*    flags  = (int*)   (ws + (size_t)20 * 1024 * 1024 + 8192);

    primes_kernel<<<(NN + 255) / 256, 256, 0, stream>>>(feat, primes);
    prep_kernel<<<(NN * NN) / 256, 256, 0, stream>>>(con, primes, S, R, C, out, flags);
    nuss_tiles_kernel<<<NTILES, 64, 0, stream>>>(R, C, S, flags);
    traceback_kernel<<<1, 256, 0, stream>>>(R, C, S, out);
}

// Round 6
// 1678.343 us; speedup vs baseline: 1.2516x; 1.0766x over previous
//
#include <hip/hip_runtime.h>

#define NN 1024
#define BT 32
#define TT 32
#define NTILES ((TT * (TT + 1)) / 2)   // 528

// ---------------------------------------------------------------------------
// Fence-free cross-XCD protocol (batched sc0sc1 MALL ops, active-spin polls).
// Round-6: 256-thread blocks (4 waves). Staging / scatter / kkloops /
// writeback split across waves; phaseB (the serial 63-step wavefront) runs
// on wave 0 unchanged from round 5. Barriers sequence Ast/Bst reuse and the
// exact (fmax, fixed-order) Pld merge => results bitwise identical.
// ---------------------------------------------------------------------------
__device__ __forceinline__ double gload_cc(const double* p) {
    double v;
    asm volatile("global_load_dwordx2 %0, %1, off sc0 sc1" : "=v"(v) : "v"(p));
    return v;
}
__device__ __forceinline__ void gstore_cc(double* p, double v) {
    asm volatile("global_store_dwordx2 %0, %1, off sc0 sc1" :: "v"(p), "v"(v));
}
__device__ __forceinline__ void gstore_flag(int* p, int v) {
    asm volatile("global_store_dword %0, %1, off sc0 sc1" :: "v"(p), "v"(v));
}
#define VWAIT0 asm volatile("s_waitcnt vmcnt(0)" ::: "memory")

__device__ __forceinline__ void waitflag2(const int* f, int a0, int b0, int a1, int b1) {
    const int* p0 = &f[(a0 * TT + b0) << 4];
    const int* p1 = &f[(a1 * TT + b1) << 4];
    double x = (double)(unsigned long long)p0;
    while (true) {
        int v0, v1;
        asm volatile("global_load_dword %0, %2, off sc0 sc1\n\t"
                     "global_load_dword %1, %3, off sc0 sc1\n\t"
                     "s_waitcnt vmcnt(0)"
                     : "=&v"(v0), "=&v"(v1)
                     : "v"(p0), "v"(p1));
        if (v0 & v1) break;
        #pragma unroll
        for (int i = 0; i < 24; ++i) x = fma(x, 1.0000000001, 1.0e-300);
    }
    asm volatile("" :: "v"(x));
    asm volatile("" ::: "memory");
}
__device__ __forceinline__ void waitflag4(const int* f, int a0, int b0, int a1, int b1,
                                          int a2, int b2, int a3, int b3) {
    const int* p0 = &f[(a0 * TT + b0) << 4];
    const int* p1 = &f[(a1 * TT + b1) << 4];
    const int* p2 = &f[(a2 * TT + b2) << 4];
    const int* p3 = &f[(a3 * TT + b3) << 4];
    double x = (double)(unsigned long long)p0;
    while (true) {
        int v0, v1, v2, v3;
        asm volatile("global_load_dword %0, %4, off sc0 sc1\n\t"
                     "global_load_dword %1, %5, off sc0 sc1\n\t"
                     "global_load_dword %2, %6, off sc0 sc1\n\t"
                     "global_load_dword %3, %7, off sc0 sc1\n\t"
                     "s_waitcnt vmcnt(0)"
                     : "=&v"(v0), "=&v"(v1), "=&v"(v2), "=&v"(v3)
                     : "v"(p0), "v"(p1), "v"(p2), "v"(p3));
        if (v0 & v1 & v2 & v3) break;
        #pragma unroll
        for (int i = 0; i < 24; ++i) x = fma(x, 1.0000000001, 1.0e-300);
    }
    asm volatile("" :: "v"(x));
    asm volatile("" ::: "memory");
}

// ---------------------------------------------------------------------------
__global__ void primes_kernel(const float* __restrict__ feat, int* __restrict__ primes) {
    int i = blockIdx.x * blockDim.x + threadIdx.x;
    if (i < NN) {
        float best = feat[i * NN];
        int arg = 0;
        for (int ch = 1; ch < 4; ++ch) {
            float v = feat[ch * NN * NN + i * NN];
            if (v > best) { best = v; arg = ch; }
        }
        const int P[4] = {2, 3, 5, 7};
        primes[i] = P[arg];
    }
}

__global__ void prep_kernel(const float* __restrict__ con, const int* __restrict__ primes,
                            float* __restrict__ S, double* __restrict__ R,
                            double* __restrict__ C, float* __restrict__ out,
                            int* __restrict__ flags) {
    int idx = blockIdx.x * blockDim.x + threadIdx.x;
    int i = idx >> 10;
    int j = idx & (NN - 1);
    float c = (con[idx] + con[j * NN + i]) * 0.5f;
    int prod = primes[i] * primes[j];
    bool canon = (prod == 14) | (prod == 15) | (prod == 35);
    int d = i - j; if (d < 0) d = -d;
    S[idx] = (canon && d >= 4) ? c : 0.0f;
    R[idx] = 0.0;
    C[idx] = 0.0;
    out[idx] = 0.0f;
    if (idx < TT * TT * 16) flags[idx] = 0;
}

// ---------------------------------------------------------------------------
// Dataflow DP, 4 waves per 32x32 tile. Exactness: every candidate is one
// fp64 add of stored values; extra candidates are dominated (-1e30+x<0<=dp,
// stale-0 + 0 = 0 <= dp); fmax is exact => bitwise == numpy. The 4-way kk
// split + barrier-ordered fmax merge is exact and deterministic.
// ---------------------------------------------------------------------------
__global__ __launch_bounds__(256) void nuss_tiles_kernel(double* __restrict__ R,
                                                         double* __restrict__ C,
                                                         const float* __restrict__ S,
                                                         int* __restrict__ flags) {
    __shared__ double DJJc[32][33];
    __shared__ double Vtc[32][33];
    __shared__ __attribute__((aligned(16))) double Ast[32][34];
    __shared__ __attribute__((aligned(16))) double Bst[32][34];
    __shared__ double Pld[32][33];
    __shared__ float  Sld[32][32];
    __shared__ double edgeCol[33];

    int b = blockIdx.x, dd = 0;
    while (b >= TT - dd) { b -= TT - dd; ++dd; }
    const int I = b, J = b + dd;
    const int aI = I * BT, aJ = J * BT;
    const int tid = threadIdx.x;
    const int wid = tid >> 6;
    const int lane = tid & 63;
    const int r = lane >> 1;
    const int h = lane & 1;

    if (dd == 0) {
        // ---------------- diagonal tile ----------------
        #pragma unroll
        for (int w = 0; w < 4; ++w) {
            int idx = w * 256 + tid; int rr = idx >> 5, cc = idx & 31;
            Sld[rr][cc] = S[(aI + rr) * NN + aI + cc];
        }
        for (int idx = tid; idx < 32 * 33; idx += 256)
            ((double*)Vtc)[idx] = 0.0;
        __syncthreads();
        if (wid == 0) {
            double vrow[16];
            #pragma unroll
            for (int u = 0; u < 16; ++u) vrow[u] = 0.0;
            for (int s = 1; s <= 31; ++s) {
                int c = r + s;
                bool act = (c <= 31);
                double acc = 0.0;
                if (act) {
                    double t0 = 0.0, t1 = 0.0, t2 = 0.0, t3 = 0.0;
                    #pragma unroll
                    for (int u = 0; u < 16; u += 4) {
                        int k0 = h * 16 + u;
                        t0 = fmax(t0, vrow[u]     + Vtc[c][k0 + 1]);
                        t1 = fmax(t1, vrow[u + 1] + Vtc[c][k0 + 2]);
                        t2 = fmax(t2, vrow[u + 2] + Vtc[c][k0 + 3]);
                        t3 = fmax(t3, vrow[u + 3] + Vtc[c][k0 + 4]);
                    }
                    acc = fmax(fmax(t0, t1), fmax(t2, t3));
                }
                acc = fmax(acc, __shfl_xor(acc, 1));
                if (act) {
                    double best = fmax(acc, Vtc[c - 1][r + 1] + (double)Sld[r][c]);
                    if (h == 0) Vtc[c][r] = best;
                    #pragma unroll
                    for (int u = 0; u < 16; ++u)
                        if (h * 16 + u == c) vrow[u] = best;
                }
            }
        }
        __syncthreads();
        #pragma unroll
        for (int w = 0; w < 4; ++w) {
            int idx = w * 256 + tid; int rr = idx >> 5, cc = idx & 31;
            gstore_cc(&R[(aI + rr) * NN + aI + cc], Vtc[cc][rr]);
        }
        #pragma unroll
        for (int w = 0; w < 4; ++w) {
            int idx = w * 256 + tid; int cc = idx >> 5, rr = idx & 31;
            gstore_cc(&C[(aI + cc) * NN + aI + rr], Vtc[cc][rr]);
        }
        VWAIT0;
        __syncthreads();
        if (tid == 0) gstore_flag(&flags[(I * TT + I) << 4], 1);
        return;
    }

    // ---------------- off-diagonal tile ----------------
    const int nk = dd - 1;
    waitflag2(flags, I, I, J, J);

    double ra[4], rb[4];
    double ec = 0.0, ve = 0.0;
    double asl[16];
    #pragma unroll
    for (int w = 0; w < 4; ++w) {
        int idx = w * 256 + tid; int cc = idx >> 5, mm = idx & 31;
        ra[w] = gload_cc(&C[(aJ + cc) * NN + aJ + mm]);
    }
    if (wid == 0) {
        #pragma unroll
        for (int u = 0; u < 16; ++u)
            asl[u] = gload_cc(&R[(aI + r) * NN + aI + h * 16 + u]);
        if (nk == 0) {
            if (lane < 33) ec = gload_cc(&R[(aI + lane) * NN + (aJ - 1)]);
            if (lane < 32) ve = gload_cc(&R[(aI + 32) * NN + aJ + lane]);
        }
    }
    #pragma unroll
    for (int w = 0; w < 4; ++w) {
        int idx = w * 256 + tid; int rr = idx >> 5, cc = idx & 31;
        Sld[rr][cc] = S[(aI + rr) * NN + aJ + cc];
    }
    for (int idx = tid; idx < 32 * 33; idx += 256)
        ((double*)Vtc)[idx] = 0.0;
    VWAIT0;
    #pragma unroll
    for (int w = 0; w < 4; ++w) {
        int idx = w * 256 + tid; int cc = idx >> 5, mm = idx & 31;
        DJJc[cc][mm] = ra[w];
    }
    if (tid < 32) DJJc[tid][32] = 0.0;
    double aslice[16];
    if (wid == 0) {
        #pragma unroll
        for (int u = 0; u < 16; ++u)
            aslice[u] = (h * 16 + u > r) ? asl[u] : -1.0e30;
    }
    __syncthreads();

    // ---- phaseA: all-wave cooperative, middle-out, readiness pairs ----
    double P[16];
    #pragma unroll
    for (int x = 0; x < 16; ++x) P[x] = 0.0;
    const int rg = lane >> 3, cg = lane & 7;
    const int r4 = rg * 4, c4 = cg * 4;

    auto kkloop = [&]() {
        for (int kk = wid * 8; kk < wid * 8 + 8; ++kk) {
            double2 av0 = *(const double2*)&Ast[kk][r4];
            double2 av1 = *(const double2*)&Ast[kk][r4 + 2];
            double2 bv0 = *(const double2*)&Bst[kk][c4];
            double2 bv1 = *(const double2*)&Bst[kk][c4 + 2];
            P[0]  = fmax(P[0],  av0.x + bv0.x); P[1]  = fmax(P[1],  av0.x + bv0.y);
            P[2]  = fmax(P[2],  av0.x + bv1.x); P[3]  = fmax(P[3],  av0.x + bv1.y);
            P[4]  = fmax(P[4],  av0.y + bv0.x); P[5]  = fmax(P[5],  av0.y + bv0.y);
            P[6]  = fmax(P[6],  av0.y + bv1.x); P[7]  = fmax(P[7],  av0.y + bv1.y);
            P[8]  = fmax(P[8],  av1.x + bv0.x); P[9]  = fmax(P[9],  av1.x + bv0.y);
            P[10] = fmax(P[10], av1.x + bv1.x); P[11] = fmax(P[11], av1.x + bv1.y);
            P[12] = fmax(P[12], av1.y + bv0.x); P[13] = fmax(P[13], av1.y + bv0.y);
            P[14] = fmax(P[14], av1.y + bv1.x); P[15] = fmax(P[15], av1.y + bv1.y);
        }
    };
    auto proc = [&](int t1, int t2, bool last) {
        if (t2 >= 0) waitflag4(flags, I, t1, t1, J, I, t2, t2, J);
        else         waitflag2(flags, I, t1, t1, J);
        if (last && wid == 0) {                       // edge prefetch (flags covered)
            if (lane < 33) ec = gload_cc(&R[(aI + lane) * NN + (aJ - 1)]);
            if (lane < 32) ve = gload_cc(&R[(aI + 32) * NN + aJ + lane]);
        }
        int k1 = t1 * BT;
        #pragma unroll
        for (int w = 0; w < 4; ++w) {
            int idx = w * 256 + tid; int rr = idx >> 5, kk = idx & 31;
            ra[w] = gload_cc(&R[(aI + rr) * NN + k1 + kk]);
            rb[w] = gload_cc(&C[(aJ + rr) * NN + k1 + 1 + kk]);
        }
        VWAIT0;
        #pragma unroll
        for (int w = 0; w < 4; ++w) {
            int idx = w * 256 + tid; int rr = idx >> 5, kk = idx & 31;
            Ast[kk][rr] = ra[w];
            Bst[kk][rr] = rb[w];
        }
        if (last && wid == 0) {
            if (lane < 33) edgeCol[lane] = ec;
            if (lane < 32) Vtc[lane][32] = ve;
        }
        __syncthreads();
        if (t2 >= 0) {
            int k2 = t2 * BT;
            #pragma unroll
            for (int w = 0; w < 4; ++w) {
                int idx = w * 256 + tid; int rr = idx >> 5, kk = idx & 31;
                ra[w] = gload_cc(&R[(aI + rr) * NN + k2 + kk]);
                rb[w] = gload_cc(&C[(aJ + rr) * NN + k2 + 1 + kk]);
            }
        }
        kkloop();
        if (t2 >= 0) {
            __syncthreads();                          // all done reading t1
            VWAIT0;
            #pragma unroll
            for (int w = 0; w < 4; ++w) {
                int idx = w * 256 + tid; int rr = idx >> 5, kk = idx & 31;
                Ast[kk][rr] = ra[w];
                Bst[kk][rr] = rb[w];
            }
            __syncthreads();
            kkloop();
        }
        __syncthreads();                              // Ast/Bst free for next proc
    };

    {
        int tl = (I + J) >> 1, tr = ((I + J) >> 1) + 1;
        int pend = -1;
        for (int q = 0; q < nk; ++q) {
            int t;
            if ((q & 1) == 0) { if (tl >= I + 1) t = tl--; else t = tr++; }
            else              { if (tr <= J - 1) t = tr++; else t = tl--; }
            if (pend < 0) { pend = t; continue; }
            int rp = (pend - I > J - pend) ? pend - I : J - pend;
            int rt = (t - I > J - t) ? t - I : J - t;
            if (rp == rt) { proc(pend, t, q == nk - 1); pend = -1; }
            else          { proc(pend, -1, false); pend = t; }
        }
        if (pend >= 0) proc(pend, -1, true);
    }

    // ---- Pld merge (exact fmax, fixed barrier order) ----
    if (nk > 0) {
        if (wid == 0) {
            #pragma unroll
            for (int x = 0; x < 4; ++x)
                #pragma unroll
                for (int y = 0; y < 4; ++y)
                    Pld[r4 + x][c4 + y] = P[x * 4 + y];
        }
        __syncthreads();
        if (wid == 1) {
            #pragma unroll
            for (int x = 0; x < 4; ++x)
                #pragma unroll
                for (int y = 0; y < 4; ++y)
                    Pld[r4 + x][c4 + y] = fmax(Pld[r4 + x][c4 + y], P[x * 4 + y]);
        }
        __syncthreads();
        if (wid == 2) {
            #pragma unroll
            for (int x = 0; x < 4; ++x)
                #pragma unroll
                for (int y = 0; y < 4; ++y)
                    Pld[r4 + x][c4 + y] = fmax(Pld[r4 + x][c4 + y], P[x * 4 + y]);
        }
        __syncthreads();
        if (wid == 3) {
            #pragma unroll
            for (int x = 0; x < 4; ++x)
                #pragma unroll
                for (int y = 0; y < 4; ++y)
                    Pld[r4 + x][c4 + y] = fmax(Pld[r4 + x][c4 + y], P[x * 4 + y]);
        }
        __syncthreads();
    } else {
        for (int idx = tid; idx < 32 * 33; idx += 256)
            ((double*)Pld)[idx] = 0.0;
        if (wid == 0) {
            if (lane < 33) edgeCol[lane] = ec;
            if (lane < 32) Vtc[lane][32] = ve;
        }
        __syncthreads();
    }

    // ---- phaseB: wave 0, software-pipelined (round-5 code verbatim) ----
    if (wid == 0) {
        double vrow[16];
        #pragma unroll
        for (int u = 0; u < 16; ++u) vrow[u] = 0.0;

        double ecr = edgeCol[r];
        double ecp = edgeCol[r + 1];

        double tvA[16], qvA[16], tvB[16], qvB[16];
        double p1 = 0.0, shc = 0.0, shp = 0.0, erc = 0.0, erp = 0.0;

#define PREFB(TV, QV, SS)                                             \
    { int cc_ = (r + (SS) - 31); cc_ = cc_ < 0 ? 0 : (cc_ > 31 ? 31 : cc_); \
      _Pragma("unroll")                                               \
      for (int u = 0; u < 16; ++u) {                                  \
          TV[u] = Vtc[cc_][h * 16 + u + 1];                           \
          QV[u] = DJJc[cc_][h * 16 + u + 1];                          \
      } }

#define STEPB(TV, QV, SS)                                             \
    { int c_ = r + (SS) - 31;                                         \
      bool act_ = ((unsigned)c_ < 32u);                               \
      int cc_ = c_ < 0 ? 0 : (c_ > 31 ? 31 : c_);                     \
      double er_  = Vtc[cc_][32];                                     \
      double dj0_ = DJJc[cc_][0];                                     \
      double pld_ = Pld[r][cc_];                                      \
      float  sld_ = Sld[r][cc_];                                      \
      shp = shc; erp = erc; erc = er_;                                \
      shc = __shfl_down(p1, 2);                                       \
      double acc_ = -1.0e30;                                          \
      if (act_) {                                                     \
          double t0_ = -1.0e30, t1_ = -1.0e30, t2_ = -1.0e30, t3_ = -1.0e30; \
          _Pragma("unroll")                                           \
          for (int u = 0; u < 16; u += 4) {                           \
              t0_ = fmax(t0_, aslice[u]     + TV[u]);                 \
              t1_ = fmax(t1_, aslice[u + 1] + TV[u + 1]);             \
              t2_ = fmax(t2_, aslice[u + 2] + TV[u + 2]);             \
              t3_ = fmax(t3_, aslice[u + 3] + TV[u + 3]);             \
          }                                                           \
          _Pragma("unroll")                                           \
          for (int u = 0; u < 16; u += 4) {                           \
              t0_ = fmax(t0_, vrow[u]     + QV[u]);                   \
              t1_ = fmax(t1_, vrow[u + 1] + QV[u + 1]);               \
              t2_ = fmax(t2_, vrow[u + 2] + QV[u + 2]);               \
              t3_ = fmax(t3_, vrow[u + 3] + QV[u + 3]);               \
          }                                                           \
          acc_ = fmax(fmax(t0_, t1_), fmax(t2_, t3_));                \
      }                                                               \
      acc_ = fmax(acc_, __shfl_xor(acc_, 1));                         \
      if (act_) {                                                     \
          double best_ = acc_;                                        \
          best_ = fmax(best_, (r == 31) ? erc : shc);                 \
          best_ = fmax(best_, ecr + dj0_);                            \
          best_ = fmax(best_, pld_);                                  \
          double pv_ = (c_ == 0) ? ecp : ((r == 31) ? erp : shp);     \
          best_ = fmax(best_, pv_ + (double)sld_);                    \
          if (h == 0) Vtc[c_][r] = best_;                             \
          _Pragma("unroll")                                           \
          for (int u = 0; u < 16; ++u)                                \
              if (h * 16 + u == c_) vrow[u] = best_;                  \
          p1 = best_;                                                 \
      } }

        PREFB(tvA, qvA, 0)
        for (int s2 = 0; s2 < 64; s2 += 2) {
            PREFB(tvB, qvB, s2 + 1)
            STEPB(tvA, qvA, s2)
            PREFB(tvA, qvA, s2 + 2)
            STEPB(tvB, qvB, s2 + 1)
        }
#undef PREFB
#undef STEPB
    }
    __syncthreads();

    // ---- writeback, 4-way split ----
    #pragma unroll
    for (int w = 0; w < 4; ++w) {
        int idx = w * 256 + tid; int rr = idx >> 5, cc = idx & 31;
        gstore_cc(&R[(aI + rr) * NN + aJ + cc], Vtc[cc][rr]);
    }
    #pragma unroll
    for (int w = 0; w < 4; ++w) {
        int idx = w * 256 + tid; int cc = idx >> 5, rr = idx & 31;
        gstore_cc(&C[(aJ + cc) * NN + aI + rr], Vtc[cc][rr]);
    }
    VWAIT0;
    __syncthreads();                                  // every wave drained
    if (tid == 0) gstore_flag(&flags[(I * TT + J) << 4], 1);
}

// ---------------------------------------------------------------------------
// Traceback, software-pipelined (unchanged).
// ---------------------------------------------------------------------------
__global__ __launch_bounds__(256) void traceback_kernel(const double* __restrict__ R,
                                                        const double* __restrict__ C,
                                                        const float* __restrict__ S,
                                                        float* __restrict__ out) {
    __shared__ int stk_i[2048];
    __shared__ int stk_j[2048];
    __shared__ double stk_v[2048];
    __shared__ int sh_top, sh_ii, sh_jj, sh_cmd;
    __shared__ double sred_v[4];
    __shared__ int sred_k[4];
    const double eps = 1e-9;
    if (threadIdx.x == 0) {
        sh_top = 1; stk_i[0] = 0; stk_j[0] = NN - 1; stk_v[0] = R[NN - 1];
    }
    __syncthreads();
    while (true) {
        if (threadIdx.x == 0) {
            int cmd = -1, top = sh_top;
            int i = 0, j = 0; double v = 0.0, a = 0.0, b2 = 0.0; float sv = 0.0f;
            bool have = false;
            while (true) {
                if (!have) {
                    if (top == 0) { cmd = -1; break; }
                    i = stk_i[--top]; j = stk_j[top]; v = stk_v[top];
                    if (j <= i || v <= eps) continue;
                    a  = R[(i + 1) * NN + j];
                    sv = S[i * NN + j];
                    b2 = R[(i + 1) * NN + j - 1];
                    have = true;
                    continue;
                }
                int ip = (i + 2 <= NN - 1) ? i + 2 : NN - 1;
                int jl = (j - 2 >= 0) ? j - 2 : 0;
                double ar = R[ip * NN + j];
                double br = R[ip * NN + j - 1];
                double bl = R[ip * NN + jl];
                float  sr = S[(i + 1) * NN + j];
                float  sl = S[(i + 1) * NN + j - 1];
                if (a >= v - eps) {
                    ++i; v = a; a = ar; sv = sr; b2 = br;
                    if (j <= i || v <= eps) have = false;
                    continue;
                }
                if (sv > 0.0f && b2 + (double)sv >= v - eps) {
                    out[i * NN + j] = sv; out[j * NN + i] = sv;
                    ++i; --j; v = b2; a = br; sv = sl; b2 = bl;
                    if (j <= i || v <= eps) have = false;
                    continue;
                }
                sh_ii = i; sh_jj = j; cmd = 0; break;
            }
            sh_top = top; sh_cmd = cmd;
        }
        __syncthreads();
        if (sh_cmd < 0) break;
        int i = sh_ii, j = sh_jj;
        double bv = -1.0; int bk = 0x7fffffff;
        for (int k = i + threadIdx.x; k < j; k += 256) {
            double tv = R[i * NN + k] + C[j * NN + k + 1];
            if (tv > bv) { bv = tv; bk = k; }
        }
        for (int off = 32; off; off >>= 1) {
            double ov = __shfl_down(bv, off);
            int   ok = __shfl_down(bk, off);
            if (ov > bv || (ov == bv && ok < bk)) { bv = ov; bk = ok; }
        }
        if ((threadIdx.x & 63) == 0) { sred_v[threadIdx.x >> 6] = bv; sred_k[threadIdx.x >> 6] = bk; }
        __syncthreads();
        if (threadIdx.x == 0) {
            double fv = sred_v[0]; int fk = sred_k[0];
            for (int w = 1; w < 4; ++w)
                if (sred_v[w] > fv || (sred_v[w] == fv && sred_k[w] < fk)) { fv = sred_v[w]; fk = sred_k[w]; }
            int top = sh_top;
            stk_i[top] = sh_ii;  stk_j[top] = fk;    stk_v[top] = R[sh_ii * NN + fk];      ++top;
            stk_i[top] = fk + 1; stk_j[top] = sh_jj; stk_v[top] = C[sh_jj * NN + fk + 1];  ++top;
            sh_top = top;
        }
        __syncthreads();
    }
}

// ---------------------------------------------------------------------------
extern "C" void kernel_launch(void* const* d_in, const int* in_sizes, int n_in,
                              void* d_out, int out_size, void* d_ws, size_t ws_size,
                              hipStream_t stream) {
    const float* con  = (const float*)d_in[0];
    const float* feat = (const float*)d_in[1];
    float* out = (float*)d_out;

    char* ws = (char*)d_ws;
    double* R      = (double*)(ws);
    double* C      = (double*)(ws + (size_t)8  * 1024 * 1024);
    float*  S      = (float*) (ws + (size_t)16 * 1024 * 1024);
    int*    primes = (int*)   (ws + (size_t)20 * 1024 * 1024);
    int*    flags  = (int*)   (ws + (size_t)20 * 1024 * 1024 + 8192);

    primes_kernel<<<(NN + 255) / 256, 256, 0, stream>>>(feat, primes);
    prep_kernel<<<(NN * NN) / 256, 256, 0, stream>>>(con, primes, S, R, C, out, flags);
    nuss_tiles_kernel<<<NTILES, 256, 0, stream>>>(R, C, S, flags);
    traceback_kernel<<<1, 256, 0, stream>>>(R, C, S, out);
}

// Round 7
// 1584.241 us; speedup vs baseline: 1.3260x; 1.0594x over previous
//
#include <hip/hip_runtime.h>

#define NN 1024
#define BT 32
#define TT 32
#define NTILES ((TT * (TT + 1)) / 2)   // 528

// ---------------------------------------------------------------------------
// Fence-free cross-XCD protocol (batched sc0sc1 MALL ops). Round-7:
//  - only wave 0 polls flags (others wait at barrier), escalating s_sleep
//  - phaseB prefetch clamp -> wrap (&31): kills clamp-induced LDS conflicts
//  - traceback: 16x16 LDS window, 1 MALL RTT per ~8-16 traceback steps
// ---------------------------------------------------------------------------
__device__ __forceinline__ double gload_cc(const double* p) {
    double v;
    asm volatile("global_load_dwordx2 %0, %1, off sc0 sc1" : "=v"(v) : "v"(p));
    return v;
}
__device__ __forceinline__ void gstore_cc(double* p, double v) {
    asm volatile("global_store_dwordx2 %0, %1, off sc0 sc1" :: "v"(p), "v"(v));
}
__device__ __forceinline__ void gstore_flag(int* p, int v) {
    asm volatile("global_store_dword %0, %1, off sc0 sc1" :: "v"(p), "v"(v));
}
#define VWAIT0 asm volatile("s_waitcnt vmcnt(0)" ::: "memory")

__device__ __forceinline__ void waitflag2(const int* f, int a0, int b0, int a1, int b1) {
    const int* p0 = &f[(a0 * TT + b0) << 4];
    const int* p1 = &f[(a1 * TT + b1) << 4];
    int it = 0;
    while (true) {
        int v0, v1;
        asm volatile("global_load_dword %0, %2, off sc0 sc1\n\t"
                     "global_load_dword %1, %3, off sc0 sc1\n\t"
                     "s_waitcnt vmcnt(0)"
                     : "=&v"(v0), "=&v"(v1)
                     : "v"(p0), "v"(p1));
        if (v0 & v1) break;
        if (it < 8) __builtin_amdgcn_s_sleep(1);
        else        __builtin_amdgcn_s_sleep(15);
        ++it;
    }
    asm volatile("" ::: "memory");
}
__device__ __forceinline__ void waitflag4(const int* f, int a0, int b0, int a1, int b1,
                                          int a2, int b2, int a3, int b3) {
    const int* p0 = &f[(a0 * TT + b0) << 4];
    const int* p1 = &f[(a1 * TT + b1) << 4];
    const int* p2 = &f[(a2 * TT + b2) << 4];
    const int* p3 = &f[(a3 * TT + b3) << 4];
    int it = 0;
    while (true) {
        int v0, v1, v2, v3;
        asm volatile("global_load_dword %0, %4, off sc0 sc1\n\t"
                     "global_load_dword %1, %5, off sc0 sc1\n\t"
                     "global_load_dword %2, %6, off sc0 sc1\n\t"
                     "global_load_dword %3, %7, off sc0 sc1\n\t"
                     "s_waitcnt vmcnt(0)"
                     : "=&v"(v0), "=&v"(v1), "=&v"(v2), "=&v"(v3)
                     : "v"(p0), "v"(p1), "v"(p2), "v"(p3));
        if (v0 & v1 & v2 & v3) break;
        if (it < 8) __builtin_amdgcn_s_sleep(1);
        else        __builtin_amdgcn_s_sleep(15);
        ++it;
    }
    asm volatile("" ::: "memory");
}
// Block-level: only wave 0 polls; barrier releases the rest (and orders the
// observation before any dependent sc0sc1 load in any wave).
__device__ __forceinline__ void waitflag2_blk(const int* f, int a0, int b0, int a1, int b1) {
    if (threadIdx.x < 64) waitflag2(f, a0, b0, a1, b1);
    __syncthreads();
}
__device__ __forceinline__ void waitflag4_blk(const int* f, int a0, int b0, int a1, int b1,
                                              int a2, int b2, int a3, int b3) {
    if (threadIdx.x < 64) waitflag4(f, a0, b0, a1, b1, a2, b2, a3, b3);
    __syncthreads();
}

// ---------------------------------------------------------------------------
__global__ void primes_kernel(const float* __restrict__ feat, int* __restrict__ primes) {
    int i = blockIdx.x * blockDim.x + threadIdx.x;
    if (i < NN) {
        float best = feat[i * NN];
        int arg = 0;
        for (int ch = 1; ch < 4; ++ch) {
            float v = feat[ch * NN * NN + i * NN];
            if (v > best) { best = v; arg = ch; }
        }
        const int P[4] = {2, 3, 5, 7};
        primes[i] = P[arg];
    }
}

__global__ void prep_kernel(const float* __restrict__ con, const int* __restrict__ primes,
                            float* __restrict__ S, double* __restrict__ R,
                            double* __restrict__ C, float* __restrict__ out,
                            int* __restrict__ flags) {
    int idx = blockIdx.x * blockDim.x + threadIdx.x;
    int i = idx >> 10;
    int j = idx & (NN - 1);
    float c = (con[idx] + con[j * NN + i]) * 0.5f;
    int prod = primes[i] * primes[j];
    bool canon = (prod == 14) | (prod == 15) | (prod == 35);
    int d = i - j; if (d < 0) d = -d;
    S[idx] = (canon && d >= 4) ? c : 0.0f;
    R[idx] = 0.0;
    C[idx] = 0.0;
    out[idx] = 0.0f;
    if (idx < TT * TT * 16) flags[idx] = 0;
}

// ---------------------------------------------------------------------------
// Dataflow DP, 4 waves per 32x32 tile. Exactness: every candidate is one
// fp64 add of stored values; extra candidates are dominated (-1e30+x<0<=dp,
// stale-0 + 0 = 0 <= dp); fmax is exact => bitwise == numpy. Wrapped (&31)
// prefetch indices are only consumed by act_ lanes, where wrap == identity.
// ---------------------------------------------------------------------------
__global__ __launch_bounds__(256) void nuss_tiles_kernel(double* __restrict__ R,
                                                         double* __restrict__ C,
                                                         const float* __restrict__ S,
                                                         int* __restrict__ flags) {
    __shared__ double DJJc[32][33];
    __shared__ double Vtc[32][33];
    __shared__ __attribute__((aligned(16))) double Ast[32][34];
    __shared__ __attribute__((aligned(16))) double Bst[32][34];
    __shared__ double Pld[32][33];
    __shared__ float  Sld[32][32];
    __shared__ double edgeCol[33];

    int b = blockIdx.x, dd = 0;
    while (b >= TT - dd) { b -= TT - dd; ++dd; }
    const int I = b, J = b + dd;
    const int aI = I * BT, aJ = J * BT;
    const int tid = threadIdx.x;
    const int wid = tid >> 6;
    const int lane = tid & 63;
    const int r = lane >> 1;
    const int h = lane & 1;

    if (dd == 0) {
        // ---------------- diagonal tile ----------------
        #pragma unroll
        for (int w = 0; w < 4; ++w) {
            int idx = w * 256 + tid; int rr = idx >> 5, cc = idx & 31;
            Sld[rr][cc] = S[(aI + rr) * NN + aI + cc];
        }
        for (int idx = tid; idx < 32 * 33; idx += 256)
            ((double*)Vtc)[idx] = 0.0;
        __syncthreads();
        if (wid == 0) {
            double vrow[16];
            #pragma unroll
            for (int u = 0; u < 16; ++u) vrow[u] = 0.0;
            for (int s = 1; s <= 31; ++s) {
                int c = r + s;
                bool act = (c <= 31);
                double acc = 0.0;
                if (act) {
                    double t0 = 0.0, t1 = 0.0, t2 = 0.0, t3 = 0.0;
                    #pragma unroll
                    for (int u = 0; u < 16; u += 4) {
                        int k0 = h * 16 + u;
                        t0 = fmax(t0, vrow[u]     + Vtc[c][k0 + 1]);
                        t1 = fmax(t1, vrow[u + 1] + Vtc[c][k0 + 2]);
                        t2 = fmax(t2, vrow[u + 2] + Vtc[c][k0 + 3]);
                        t3 = fmax(t3, vrow[u + 3] + Vtc[c][k0 + 4]);
                    }
                    acc = fmax(fmax(t0, t1), fmax(t2, t3));
                }
                acc = fmax(acc, __shfl_xor(acc, 1));
                if (act) {
                    double best = fmax(acc, Vtc[c - 1][r + 1] + (double)Sld[r][c]);
                    if (h == 0) Vtc[c][r] = best;
                    #pragma unroll
                    for (int u = 0; u < 16; ++u)
                        if (h * 16 + u == c) vrow[u] = best;
                }
            }
        }
        __syncthreads();
        #pragma unroll
        for (int w = 0; w < 4; ++w) {
            int idx = w * 256 + tid; int rr = idx >> 5, cc = idx & 31;
            gstore_cc(&R[(aI + rr) * NN + aI + cc], Vtc[cc][rr]);
        }
        #pragma unroll
        for (int w = 0; w < 4; ++w) {
            int idx = w * 256 + tid; int cc = idx >> 5, rr = idx & 31;
            gstore_cc(&C[(aI + cc) * NN + aI + rr], Vtc[cc][rr]);
        }
        VWAIT0;
        __syncthreads();
        if (tid == 0) gstore_flag(&flags[(I * TT + I) << 4], 1);
        return;
    }

    // ---------------- off-diagonal tile ----------------
    const int nk = dd - 1;
    waitflag2_blk(flags, I, I, J, J);

    double ra[4], rb[4];
    double ec = 0.0, ve = 0.0;
    double asl[16];
    #pragma unroll
    for (int w = 0; w < 4; ++w) {
        int idx = w * 256 + tid; int cc = idx >> 5, mm = idx & 31;
        ra[w] = gload_cc(&C[(aJ + cc) * NN + aJ + mm]);
    }
    if (wid == 0) {
        #pragma unroll
        for (int u = 0; u < 16; ++u)
            asl[u] = gload_cc(&R[(aI + r) * NN + aI + h * 16 + u]);
        if (nk == 0) {
            if (lane < 33) ec = gload_cc(&R[(aI + lane) * NN + (aJ - 1)]);
            if (lane < 32) ve = gload_cc(&R[(aI + 32) * NN + aJ + lane]);
        }
    }
    #pragma unroll
    for (int w = 0; w < 4; ++w) {
        int idx = w * 256 + tid; int rr = idx >> 5, cc = idx & 31;
        Sld[rr][cc] = S[(aI + rr) * NN + aJ + cc];
    }
    for (int idx = tid; idx < 32 * 33; idx += 256)
        ((double*)Vtc)[idx] = 0.0;
    VWAIT0;
    #pragma unroll
    for (int w = 0; w < 4; ++w) {
        int idx = w * 256 + tid; int cc = idx >> 5, mm = idx & 31;
        DJJc[cc][mm] = ra[w];
    }
    if (tid < 32) DJJc[tid][32] = 0.0;
    double aslice[16];
    if (wid == 0) {
        #pragma unroll
        for (int u = 0; u < 16; ++u)
            aslice[u] = (h * 16 + u > r) ? asl[u] : -1.0e30;
    }
    __syncthreads();

    // ---- phaseA: all-wave cooperative, middle-out, readiness pairs ----
    double P[16];
    #pragma unroll
    for (int x = 0; x < 16; ++x) P[x] = 0.0;
    const int rg = lane >> 3, cg = lane & 7;
    const int r4 = rg * 4, c4 = cg * 4;

    auto kkloop = [&]() {
        for (int kk = wid * 8; kk < wid * 8 + 8; ++kk) {
            double2 av0 = *(const double2*)&Ast[kk][r4];
            double2 av1 = *(const double2*)&Ast[kk][r4 + 2];
            double2 bv0 = *(const double2*)&Bst[kk][c4];
            double2 bv1 = *(const double2*)&Bst[kk][c4 + 2];
            P[0]  = fmax(P[0],  av0.x + bv0.x); P[1]  = fmax(P[1],  av0.x + bv0.y);
            P[2]  = fmax(P[2],  av0.x + bv1.x); P[3]  = fmax(P[3],  av0.x + bv1.y);
            P[4]  = fmax(P[4],  av0.y + bv0.x); P[5]  = fmax(P[5],  av0.y + bv0.y);
            P[6]  = fmax(P[6],  av0.y + bv1.x); P[7]  = fmax(P[7],  av0.y + bv1.y);
            P[8]  = fmax(P[8],  av1.x + bv0.x); P[9]  = fmax(P[9],  av1.x + bv0.y);
            P[10] = fmax(P[10], av1.x + bv1.x); P[11] = fmax(P[11], av1.x + bv1.y);
            P[12] = fmax(P[12], av1.y + bv0.x); P[13] = fmax(P[13], av1.y + bv0.y);
            P[14] = fmax(P[14], av1.y + bv1.x); P[15] = fmax(P[15], av1.y + bv1.y);
        }
    };
    auto proc = [&](int t1, int t2, bool last) {
        if (t2 >= 0) waitflag4_blk(flags, I, t1, t1, J, I, t2, t2, J);
        else         waitflag2_blk(flags, I, t1, t1, J);
        if (last && wid == 0) {                       // edge prefetch (flags covered)
            if (lane < 33) ec = gload_cc(&R[(aI + lane) * NN + (aJ - 1)]);
            if (lane < 32) ve = gload_cc(&R[(aI + 32) * NN + aJ + lane]);
        }
        int k1 = t1 * BT;
        #pragma unroll
        for (int w = 0; w < 4; ++w) {
            int idx = w * 256 + tid; int rr = idx >> 5, kk = idx & 31;
            ra[w] = gload_cc(&R[(aI + rr) * NN + k1 + kk]);
            rb[w] = gload_cc(&C[(aJ + rr) * NN + k1 + 1 + kk]);
        }
        VWAIT0;
        #pragma unroll
        for (int w = 0; w < 4; ++w) {
            int idx = w * 256 + tid; int rr = idx >> 5, kk = idx & 31;
            Ast[kk][rr] = ra[w];
            Bst[kk][rr] = rb[w];
        }
        if (last && wid == 0) {
            if (lane < 33) edgeCol[lane] = ec;
            if (lane < 32) Vtc[lane][32] = ve;
        }
        __syncthreads();
        if (t2 >= 0) {
            int k2 = t2 * BT;
            #pragma unroll
            for (int w = 0; w < 4; ++w) {
                int idx = w * 256 + tid; int rr = idx >> 5, kk = idx & 31;
                ra[w] = gload_cc(&R[(aI + rr) * NN + k2 + kk]);
                rb[w] = gload_cc(&C[(aJ + rr) * NN + k2 + 1 + kk]);
            }
        }
        kkloop();
        if (t2 >= 0) {
            __syncthreads();                          // all done reading t1
            VWAIT0;
            #pragma unroll
            for (int w = 0; w < 4; ++w) {
                int idx = w * 256 + tid; int rr = idx >> 5, kk = idx & 31;
                Ast[kk][rr] = ra[w];
                Bst[kk][rr] = rb[w];
            }
            __syncthreads();
            kkloop();
        }
        __syncthreads();                              // Ast/Bst free for next proc
    };

    {
        int tl = (I + J) >> 1, tr = ((I + J) >> 1) + 1;
        int pend = -1;
        for (int q = 0; q < nk; ++q) {
            int t;
            if ((q & 1) == 0) { if (tl >= I + 1) t = tl--; else t = tr++; }
            else              { if (tr <= J - 1) t = tr++; else t = tl--; }
            if (pend < 0) { pend = t; continue; }
            int rp = (pend - I > J - pend) ? pend - I : J - pend;
            int rt = (t - I > J - t) ? t - I : J - t;
            if (rp == rt) { proc(pend, t, q == nk - 1); pend = -1; }
            else          { proc(pend, -1, false); pend = t; }
        }
        if (pend >= 0) proc(pend, -1, true);
    }

    // ---- Pld merge (exact fmax, fixed barrier order) ----
    if (nk > 0) {
        if (wid == 0) {
            #pragma unroll
            for (int x = 0; x < 4; ++x)
                #pragma unroll
                for (int y = 0; y < 4; ++y)
                    Pld[r4 + x][c4 + y] = P[x * 4 + y];
        }
        __syncthreads();
        if (wid == 1) {
            #pragma unroll
            for (int x = 0; x < 4; ++x)
                #pragma unroll
                for (int y = 0; y < 4; ++y)
                    Pld[r4 + x][c4 + y] = fmax(Pld[r4 + x][c4 + y], P[x * 4 + y]);
        }
        __syncthreads();
        if (wid == 2) {
            #pragma unroll
            for (int x = 0; x < 4; ++x)
                #pragma unroll
                for (int y = 0; y < 4; ++y)
                    Pld[r4 + x][c4 + y] = fmax(Pld[r4 + x][c4 + y], P[x * 4 + y]);
        }
        __syncthreads();
        if (wid == 3) {
            #pragma unroll
            for (int x = 0; x < 4; ++x)
                #pragma unroll
                for (int y = 0; y < 4; ++y)
                    Pld[r4 + x][c4 + y] = fmax(Pld[r4 + x][c4 + y], P[x * 4 + y]);
        }
        __syncthreads();
    } else {
        for (int idx = tid; idx < 32 * 33; idx += 256)
            ((double*)Pld)[idx] = 0.0;
        if (wid == 0) {
            if (lane < 33) edgeCol[lane] = ec;
            if (lane < 32) Vtc[lane][32] = ve;
        }
        __syncthreads();
    }

    // ---- phaseB: wave 0, software-pipelined; wrapped (&31) prefetch ----
    if (wid == 0) {
        double vrow[16];
        #pragma unroll
        for (int u = 0; u < 16; ++u) vrow[u] = 0.0;

        double ecr = edgeCol[r];
        double ecp = edgeCol[r + 1];

        double tvA[16], qvA[16], tvB[16], qvB[16];
        double p1 = 0.0, shc = 0.0, shp = 0.0, erc = 0.0, erp = 0.0;

#define PREFB(TV, QV, SS)                                             \
    { int cc_ = (r + (SS) - 31) & 31;                                 \
      _Pragma("unroll")                                               \
      for (int u = 0; u < 16; ++u) {                                  \
          TV[u] = Vtc[cc_][h * 16 + u + 1];                           \
          QV[u] = DJJc[cc_][h * 16 + u + 1];                          \
      } }

#define STEPB(TV, QV, SS)                                             \
    { int c_ = r + (SS) - 31;                                         \
      bool act_ = ((unsigned)c_ < 32u);                               \
      int cc_ = c_ & 31;                                              \
      double er_  = Vtc[cc_][32];                                     \
      double dj0_ = DJJc[cc_][0];                                     \
      double pld_ = Pld[r][cc_];                                      \
      float  sld_ = Sld[r][cc_];                                      \
      shp = shc; erp = erc; erc = er_;                                \
      shc = __shfl_down(p1, 2);                                       \
      double acc_ = -1.0e30;                                          \
      if (act_) {                                                     \
          double t0_ = -1.0e30, t1_ = -1.0e30, t2_ = -1.0e30, t3_ = -1.0e30; \
          _Pragma("unroll")                                           \
          for (int u = 0; u < 16; u += 4) {                           \
              t0_ = fmax(t0_, aslice[u]     + TV[u]);                 \
              t1_ = fmax(t1_, aslice[u + 1] + TV[u + 1]);             \
              t2_ = fmax(t2_, aslice[u + 2] + TV[u + 2]);             \
              t3_ = fmax(t3_, aslice[u + 3] + TV[u + 3]);             \
          }                                                           \
          _Pragma("unroll")                                           \
          for (int u = 0; u < 16; u += 4) {                           \
              t0_ = fmax(t0_, vrow[u]     + QV[u]);                   \
              t1_ = fmax(t1_, vrow[u + 1] + QV[u + 1]);               \
              t2_ = fmax(t2_, vrow[u + 2] + QV[u + 2]);               \
              t3_ = fmax(t3_, vrow[u + 3] + QV[u + 3]);               \
          }                                                           \
          acc_ = fmax(fmax(t0_, t1_), fmax(t2_, t3_));                \
      }                                                               \
      acc_ = fmax(acc_, __shfl_xor(acc_, 1));                         \
      if (act_) {                                                     \
          double best_ = acc_;                                        \
          best_ = fmax(best_, (r == 31) ? erc : shc);                 \
          best_ = fmax(best_, ecr + dj0_);                            \
          best_ = fmax(best_, pld_);                                  \
          double pv_ = (c_ == 0) ? ecp : ((r == 31) ? erp : shp);     \
          best_ = fmax(best_, pv_ + (double)sld_);                    \
          if (h == 0) Vtc[c_][r] = best_;                             \
          _Pragma("unroll")                                           \
          for (int u = 0; u < 16; ++u)                                \
              if (h * 16 + u == c_) vrow[u] = best_;                  \
          p1 = best_;                                                 \
      } }

        PREFB(tvA, qvA, 0)
        for (int s2 = 0; s2 < 64; s2 += 2) {
            PREFB(tvB, qvB, s2 + 1)
            STEPB(tvA, qvA, s2)
            PREFB(tvA, qvA, s2 + 2)
            STEPB(tvB, qvB, s2 + 1)
        }
#undef PREFB
#undef STEPB
    }
    __syncthreads();

    // ---- writeback, 4-way split ----
    #pragma unroll
    for (int w = 0; w < 4; ++w) {
        int idx = w * 256 + tid; int rr = idx >> 5, cc = idx & 31;
        gstore_cc(&R[(aI + rr) * NN + aJ + cc], Vtc[cc][rr]);
    }
    #pragma unroll
    for (int w = 0; w < 4; ++w) {
        int idx = w * 256 + tid; int cc = idx >> 5, rr = idx & 31;
        gstore_cc(&C[(aJ + cc) * NN + aI + rr], Vtc[cc][rr]);
    }
    VWAIT0;
    __syncthreads();                                  // every wave drained
    if (tid == 0) gstore_flag(&flags[(I * TT + J) << 4], 1);
}

// ---------------------------------------------------------------------------
// Traceback with a 16x16 LDS window: the serial descent/pair walk runs at
// LDS speed; one coalesced 256-thread refill (1 MALL RTT) per window. All
// consumed window entries are exactly the addresses the original code read
// (clamped entries are never consumed: reads require j>i>=0 within window).
// ---------------------------------------------------------------------------
__global__ __launch_bounds__(256) void traceback_kernel(const double* __restrict__ R,
                                                        const double* __restrict__ C,
                                                        const float* __restrict__ S,
                                                        float* __restrict__ out) {
    __shared__ int stk_i[2048];
    __shared__ int stk_j[2048];
    __shared__ double stk_v[2048];
    __shared__ double Rw[16][17];
    __shared__ float  Sw[16][17];
    __shared__ int sh_top, sh_ii, sh_jj, sh_cmd;
    __shared__ double sred_v[4];
    __shared__ int sred_k[4];
    const double eps = 1e-9;
    const int tid = threadIdx.x;

    int i = 0, j = 0; double v = 0.0; bool have = false;
    int ai = -(1 << 29), aj = 0;                      // invalid anchor -> refill

    if (tid == 0) {
        sh_top = 1; stk_i[0] = 0; stk_j[0] = NN - 1; stk_v[0] = R[NN - 1];
    }
    __syncthreads();

    while (true) {
        if (tid == 0) {
            int cmd = -1, top = sh_top;
            while (true) {
                if (!have) {
                    if (top == 0) { cmd = -1; break; }
                    i = stk_i[--top]; j = stk_j[top]; v = stk_v[top];
                    if (j <= i || v <= eps) continue;
                    have = true;
                }
                int u = i - ai, w = aj - j;
                if ((unsigned)u > 15u || (unsigned)w > 14u) { cmd = 1; break; }
                double a = Rw[u][w];                  // R[(i+1)*NN + j]
                if (a >= v - eps) {
                    ++i; v = a;
                    if (j <= i || v <= eps) have = false;
                    continue;
                }
                float sv = Sw[u][w];                  // S[i*NN + j]
                double b2 = Rw[u][w + 1];             // R[(i+1)*NN + j-1]
                if (sv > 0.0f && b2 + (double)sv >= v - eps) {
                    out[i * NN + j] = sv; out[j * NN + i] = sv;
                    ++i; --j; v = b2;
                    if (j <= i || v <= eps) have = false;
                    continue;
                }
                cmd = 0; break;                       // split
            }
            sh_top = top; sh_cmd = cmd; sh_ii = i; sh_jj = j;
        }
        __syncthreads();
        int cmd = sh_cmd;
        if (cmd < 0) break;

        if (cmd == 1) {                               // refill window at (i,j)
            int i0 = sh_ii, j0 = sh_jj;
            int di = tid >> 4, dj = tid & 15;
            int rr = i0 + 1 + di; if (rr > NN - 1) rr = NN - 1;
            int cc = j0 - dj;     if (cc < 0) cc = 0;
            Rw[di][dj] = R[rr * NN + cc];
            int sr = i0 + di;     if (sr > NN - 1) sr = NN - 1;
            Sw[di][dj] = S[sr * NN + cc];
            __syncthreads();
            ai = i0; aj = j0;                         // thread-local anchors
            continue;
        }

        // cmd == 0: split via parallel argmax (first-max = smallest k)
        const int si = sh_ii, sj = sh_jj;
        double bv = -1.0; int bk = 0x7fffffff;
        for (int k = si + tid; k < sj; k += 256) {
            double tv = R[si * NN + k] + C[sj * NN + k + 1];
            if (tv > bv) { bv = tv; bk = k; }
        }
        for (int off = 32; off; off >>= 1) {
            double ov = __shfl_down(bv, off);
            int   ok = __shfl_down(bk, off);
            if (ov > bv || (ov == bv && ok < bk)) { bv = ov; bk = ok; }
        }
        if ((tid & 63) == 0) { sred_v[tid >> 6] = bv; sred_k[tid >> 6] = bk; }
        __syncthreads();
        if (tid == 0) {
            double fv = sred_v[0]; int fk = sred_k[0];
            for (int w = 1; w < 4; ++w)
                if (sred_v[w] > fv || (sred_v[w] == fv && sred_k[w] < fk)) { fv = sred_v[w]; fk = sred_k[w]; }
            int top = sh_top;
            stk_i[top] = si;     stk_j[top] = fk; stk_v[top] = R[si * NN + fk];      ++top;
            stk_i[top] = fk + 1; stk_j[top] = sj; stk_v[top] = C[sj * NN + fk + 1];  ++top;
            sh_top = top;
            have = false;                             // state consumed
        }
        __syncthreads();
    }
}

// ---------------------------------------------------------------------------
extern "C" void kernel_launch(void* const* d_in, const int* in_sizes, int n_in,
                              void* d_out, int out_size, void* d_ws, size_t ws_size,
                              hipStream_t stream) {
    const float* con  = (const float*)d_in[0];
    const float* feat = (const float*)d_in[1];
    float* out = (float*)d_out;

    char* ws = (char*)d_ws;
    double* R      = (double*)(ws);
    double* C      = (double*)(ws + (size_t)8  * 1024 * 1024);
    float*  S      = (float*) (ws + (size_t)16 * 1024 * 1024);
    int*    primes = (int*)   (ws + (size_t)20 * 1024 * 1024);
    int*    flags  = (int*)   (ws + (size_t)20 * 1024 * 1024 + 8192);

    primes_kernel<<<(NN + 255) / 256, 256, 0, stream>>>(feat, primes);
    prep_kernel<<<(NN * NN) / 256, 256, 0, stream>>>(con, primes, S, R, C, out, flags);
    nuss_tiles_kernel<<<NTILES, 256, 0, stream>>>(R, C, S, flags);
    traceback_kernel<<<1, 256, 0, stream>>>(R, C, S, out);
}

// Round 9
// 1299.631 us; speedup vs baseline: 1.6163x; 1.2190x over previous
//
#include <hip/hip_runtime.h>

#define NN 1024
#define BT 32
#define TT 32
#define NTILES ((TT * (TT + 1)) / 2)   // 528

// ---------------------------------------------------------------------------
// Fence-free cross-XCD protocol (batched sc0sc1 MALL ops). Round-9:
// round-8's parallel traceback with a HARDENED queue protocol:
//  - push ordering: qi/qj stores -> vmcnt(0) -> pending+1 -> vmcnt(0) ->
//    ready=1  (pending increment now provably visible before the flag, so
//    pending==0 is a sound global-termination signal)
//  - watchdog on the idle poll (2^22 iters) -> clean exit, never a GPU hang
// nuss_tiles_kernel is UNCHANGED from round 7 (verified 1169 us).
// ---------------------------------------------------------------------------
__device__ __forceinline__ double gload_cc(const double* p) {
    double v;
    asm volatile("global_load_dwordx2 %0, %1, off sc0 sc1" : "=v"(v) : "v"(p));
    return v;
}
__device__ __forceinline__ void gstore_cc(double* p, double v) {
    asm volatile("global_store_dwordx2 %0, %1, off sc0 sc1" :: "v"(p), "v"(v));
}
__device__ __forceinline__ void gstore_flag(int* p, int v) {
    asm volatile("global_store_dword %0, %1, off sc0 sc1" :: "v"(p), "v"(v));
}
#define VWAIT0 asm volatile("s_waitcnt vmcnt(0)" ::: "memory")

__device__ __forceinline__ void waitflag2(const int* f, int a0, int b0, int a1, int b1) {
    const int* p0 = &f[(a0 * TT + b0) << 4];
    const int* p1 = &f[(a1 * TT + b1) << 4];
    int it = 0;
    while (true) {
        int v0, v1;
        asm volatile("global_load_dword %0, %2, off sc0 sc1\n\t"
                     "global_load_dword %1, %3, off sc0 sc1\n\t"
                     "s_waitcnt vmcnt(0)"
                     : "=&v"(v0), "=&v"(v1)
                     : "v"(p0), "v"(p1));
        if (v0 & v1) break;
        if (it < 8) __builtin_amdgcn_s_sleep(1);
        else        __builtin_amdgcn_s_sleep(15);
        ++it;
    }
    asm volatile("" ::: "memory");
}
__device__ __forceinline__ void waitflag4(const int* f, int a0, int b0, int a1, int b1,
                                          int a2, int b2, int a3, int b3) {
    const int* p0 = &f[(a0 * TT + b0) << 4];
    const int* p1 = &f[(a1 * TT + b1) << 4];
    const int* p2 = &f[(a2 * TT + b2) << 4];
    const int* p3 = &f[(a3 * TT + b3) << 4];
    int it = 0;
    while (true) {
        int v0, v1, v2, v3;
        asm volatile("global_load_dword %0, %4, off sc0 sc1\n\t"
                     "global_load_dword %1, %5, off sc0 sc1\n\t"
                     "global_load_dword %2, %6, off sc0 sc1\n\t"
                     "global_load_dword %3, %7, off sc0 sc1\n\t"
                     "s_waitcnt vmcnt(0)"
                     : "=&v"(v0), "=&v"(v1), "=&v"(v2), "=&v"(v3)
                     : "v"(p0), "v"(p1), "v"(p2), "v"(p3));
        if (v0 & v1 & v2 & v3) break;
        if (it < 8) __builtin_amdgcn_s_sleep(1);
        else        __builtin_amdgcn_s_sleep(15);
        ++it;
    }
    asm volatile("" ::: "memory");
}
__device__ __forceinline__ void waitflag2_blk(const int* f, int a0, int b0, int a1, int b1) {
    if (threadIdx.x < 64) waitflag2(f, a0, b0, a1, b1);
    __syncthreads();
}
__device__ __forceinline__ void waitflag4_blk(const int* f, int a0, int b0, int a1, int b1,
                                              int a2, int b2, int a3, int b3) {
    if (threadIdx.x < 64) waitflag4(f, a0, b0, a1, b1, a2, b2, a3, b3);
    __syncthreads();
}

// ---------------------------------------------------------------------------
__global__ void primes_kernel(const float* __restrict__ feat, int* __restrict__ primes) {
    int i = blockIdx.x * blockDim.x + threadIdx.x;
    if (i < NN) {
        float best = feat[i * NN];
        int arg = 0;
        for (int ch = 1; ch < 4; ++ch) {
            float v = feat[ch * NN * NN + i * NN];
            if (v > best) { best = v; arg = ch; }
        }
        const int P[4] = {2, 3, 5, 7};
        primes[i] = P[arg];
    }
}

__global__ void prep_kernel(const float* __restrict__ con, const int* __restrict__ primes,
                            float* __restrict__ S, double* __restrict__ R,
                            double* __restrict__ C, float* __restrict__ out,
                            int* __restrict__ flags,
                            int* __restrict__ qi, int* __restrict__ qj,
                            int* __restrict__ qready, int* __restrict__ qctl) {
    int idx = blockIdx.x * blockDim.x + threadIdx.x;
    int i = idx >> 10;
    int j = idx & (NN - 1);
    float c = (con[idx] + con[j * NN + i]) * 0.5f;
    int prod = primes[i] * primes[j];
    bool canon = (prod == 14) | (prod == 15) | (prod == 35);
    int d = i - j; if (d < 0) d = -d;
    S[idx] = (canon && d >= 4) ? c : 0.0f;
    R[idx] = 0.0;
    C[idx] = 0.0;
    out[idx] = 0.0f;
    if (idx < TT * TT * 16) flags[idx] = 0;
    if (idx < 4096) qready[idx] = (idx == 0) ? 1 : 0;
    if (idx == 0) {
        qi[0] = 0; qj[0] = NN - 1;
        qctl[0] = 0;      // head
        qctl[16] = 1;     // tail
        qctl[32] = 1;     // pending
    }
}

// ---------------------------------------------------------------------------
// Dataflow DP, 4 waves per 32x32 tile (UNCHANGED from round 7).
// ---------------------------------------------------------------------------
__global__ __launch_bounds__(256) void nuss_tiles_kernel(double* __restrict__ R,
                                                         double* __restrict__ C,
                                                         const float* __restrict__ S,
                                                         int* __restrict__ flags) {
    __shared__ double DJJc[32][33];
    __shared__ double Vtc[32][33];
    __shared__ __attribute__((aligned(16))) double Ast[32][34];
    __shared__ __attribute__((aligned(16))) double Bst[32][34];
    __shared__ double Pld[32][33];
    __shared__ float  Sld[32][32];
    __shared__ double edgeCol[33];

    int b = blockIdx.x, dd = 0;
    while (b >= TT - dd) { b -= TT - dd; ++dd; }
    const int I = b, J = b + dd;
    const int aI = I * BT, aJ = J * BT;
    const int tid = threadIdx.x;
    const int wid = tid >> 6;
    const int lane = tid & 63;
    const int r = lane >> 1;
    const int h = lane & 1;

    if (dd == 0) {
        #pragma unroll
        for (int w = 0; w < 4; ++w) {
            int idx = w * 256 + tid; int rr = idx >> 5, cc = idx & 31;
            Sld[rr][cc] = S[(aI + rr) * NN + aI + cc];
        }
        for (int idx = tid; idx < 32 * 33; idx += 256)
            ((double*)Vtc)[idx] = 0.0;
        __syncthreads();
        if (wid == 0) {
            double vrow[16];
            #pragma unroll
            for (int u = 0; u < 16; ++u) vrow[u] = 0.0;
            for (int s = 1; s <= 31; ++s) {
                int c = r + s;
                bool act = (c <= 31);
                double acc = 0.0;
                if (act) {
                    double t0 = 0.0, t1 = 0.0, t2 = 0.0, t3 = 0.0;
                    #pragma unroll
                    for (int u = 0; u < 16; u += 4) {
                        int k0 = h * 16 + u;
                        t0 = fmax(t0, vrow[u]     + Vtc[c][k0 + 1]);
                        t1 = fmax(t1, vrow[u + 1] + Vtc[c][k0 + 2]);
                        t2 = fmax(t2, vrow[u + 2] + Vtc[c][k0 + 3]);
                        t3 = fmax(t3, vrow[u + 3] + Vtc[c][k0 + 4]);
                    }
                    acc = fmax(fmax(t0, t1), fmax(t2, t3));
                }
                acc = fmax(acc, __shfl_xor(acc, 1));
                if (act) {
                    double best = fmax(acc, Vtc[c - 1][r + 1] + (double)Sld[r][c]);
                    if (h == 0) Vtc[c][r] = best;
                    #pragma unroll
                    for (int u = 0; u < 16; ++u)
                        if (h * 16 + u == c) vrow[u] = best;
                }
            }
        }
        __syncthreads();
        #pragma unroll
        for (int w = 0; w < 4; ++w) {
            int idx = w * 256 + tid; int rr = idx >> 5, cc = idx & 31;
            gstore_cc(&R[(aI + rr) * NN + aI + cc], Vtc[cc][rr]);
        }
        #pragma unroll
        for (int w = 0; w < 4; ++w) {
            int idx = w * 256 + tid; int cc = idx >> 5, rr = idx & 31;
            gstore_cc(&C[(aI + cc) * NN + aI + rr], Vtc[cc][rr]);
        }
        VWAIT0;
        __syncthreads();
        if (tid == 0) gstore_flag(&flags[(I * TT + I) << 4], 1);
        return;
    }

    const int nk = dd - 1;
    waitflag2_blk(flags, I, I, J, J);

    double ra[4], rb[4];
    double ec = 0.0, ve = 0.0;
    double asl[16];
    #pragma unroll
    for (int w = 0; w < 4; ++w) {
        int idx = w * 256 + tid; int cc = idx >> 5, mm = idx & 31;
        ra[w] = gload_cc(&C[(aJ + cc) * NN + aJ + mm]);
    }
    if (wid == 0) {
        #pragma unroll
        for (int u = 0; u < 16; ++u)
            asl[u] = gload_cc(&R[(aI + r) * NN + aI + h * 16 + u]);
        if (nk == 0) {
            if (lane < 33) ec = gload_cc(&R[(aI + lane) * NN + (aJ - 1)]);
            if (lane < 32) ve = gload_cc(&R[(aI + 32) * NN + aJ + lane]);
        }
    }
    #pragma unroll
    for (int w = 0; w < 4; ++w) {
        int idx = w * 256 + tid; int rr = idx >> 5, cc = idx & 31;
        Sld[rr][cc] = S[(aI + rr) * NN + aJ + cc];
    }
    for (int idx = tid; idx < 32 * 33; idx += 256)
        ((double*)Vtc)[idx] = 0.0;
    VWAIT0;
    #pragma unroll
    for (int w = 0; w < 4; ++w) {
        int idx = w * 256 + tid; int cc = idx >> 5, mm = idx & 31;
        DJJc[cc][mm] = ra[w];
    }
    if (tid < 32) DJJc[tid][32] = 0.0;
    double aslice[16];
    if (wid == 0) {
        #pragma unroll
        for (int u = 0; u < 16; ++u)
            aslice[u] = (h * 16 + u > r) ? asl[u] : -1.0e30;
    }
    __syncthreads();

    double P[16];
    #pragma unroll
    for (int x = 0; x < 16; ++x) P[x] = 0.0;
    const int rg = lane >> 3, cg = lane & 7;
    const int r4 = rg * 4, c4 = cg * 4;

    auto kkloop = [&]() {
        for (int kk = wid * 8; kk < wid * 8 + 8; ++kk) {
            double2 av0 = *(const double2*)&Ast[kk][r4];
            double2 av1 = *(const double2*)&Ast[kk][r4 + 2];
            double2 bv0 = *(const double2*)&Bst[kk][c4];
            double2 bv1 = *(const double2*)&Bst[kk][c4 + 2];
            P[0]  = fmax(P[0],  av0.x + bv0.x); P[1]  = fmax(P[1],  av0.x + bv0.y);
            P[2]  = fmax(P[2],  av0.x + bv1.x); P[3]  = fmax(P[3],  av0.x + bv1.y);
            P[4]  = fmax(P[4],  av0.y + bv0.x); P[5]  = fmax(P[5],  av0.y + bv0.y);
            P[6]  = fmax(P[6],  av0.y + bv1.x); P[7]  = fmax(P[7],  av0.y + bv1.y);
            P[8]  = fmax(P[8],  av1.x + bv0.x); P[9]  = fmax(P[9],  av1.x + bv0.y);
            P[10] = fmax(P[10], av1.x + bv1.x); P[11] = fmax(P[11], av1.x + bv1.y);
            P[12] = fmax(P[12], av1.y + bv0.x); P[13] = fmax(P[13], av1.y + bv0.y);
            P[14] = fmax(P[14], av1.y + bv1.x); P[15] = fmax(P[15], av1.y + bv1.y);
        }
    };
    auto proc = [&](int t1, int t2, bool last) {
        if (t2 >= 0) waitflag4_blk(flags, I, t1, t1, J, I, t2, t2, J);
        else         waitflag2_blk(flags, I, t1, t1, J);
        if (last && wid == 0) {
            if (lane < 33) ec = gload_cc(&R[(aI + lane) * NN + (aJ - 1)]);
            if (lane < 32) ve = gload_cc(&R[(aI + 32) * NN + aJ + lane]);
        }
        int k1 = t1 * BT;
        #pragma unroll
        for (int w = 0; w < 4; ++w) {
            int idx = w * 256 + tid; int rr = idx >> 5, kk = idx & 31;
            ra[w] = gload_cc(&R[(aI + rr) * NN + k1 + kk]);
            rb[w] = gload_cc(&C[(aJ + rr) * NN + k1 + 1 + kk]);
        }
        VWAIT0;
        #pragma unroll
        for (int w = 0; w < 4; ++w) {
            int idx = w * 256 + tid; int rr = idx >> 5, kk = idx & 31;
            Ast[kk][rr] = ra[w];
            Bst[kk][rr] = rb[w];
        }
        if (last && wid == 0) {
            if (lane < 33) edgeCol[lane] = ec;
            if (lane < 32) Vtc[lane][32] = ve;
        }
        __syncthreads();
        if (t2 >= 0) {
            int k2 = t2 * BT;
            #pragma unroll
            for (int w = 0; w < 4; ++w) {
                int idx = w * 256 + tid; int rr = idx >> 5, kk = idx & 31;
                ra[w] = gload_cc(&R[(aI + rr) * NN + k2 + kk]);
                rb[w] = gload_cc(&C[(aJ + rr) * NN + k2 + 1 + kk]);
            }
        }
        kkloop();
        if (t2 >= 0) {
            __syncthreads();
            VWAIT0;
            #pragma unroll
            for (int w = 0; w < 4; ++w) {
                int idx = w * 256 + tid; int rr = idx >> 5, kk = idx & 31;
                Ast[kk][rr] = ra[w];
                Bst[kk][rr] = rb[w];
            }
            __syncthreads();
            kkloop();
        }
        __syncthreads();
    };

    {
        int tl = (I + J) >> 1, tr = ((I + J) >> 1) + 1;
        int pend = -1;
        for (int q = 0; q < nk; ++q) {
            int t;
            if ((q & 1) == 0) { if (tl >= I + 1) t = tl--; else t = tr++; }
            else              { if (tr <= J - 1) t = tr++; else t = tl--; }
            if (pend < 0) { pend = t; continue; }
            int rp = (pend - I > J - pend) ? pend - I : J - pend;
            int rt = (t - I > J - t) ? t - I : J - t;
            if (rp == rt) { proc(pend, t, q == nk - 1); pend = -1; }
            else          { proc(pend, -1, false); pend = t; }
        }
        if (pend >= 0) proc(pend, -1, true);
    }

    if (nk > 0) {
        if (wid == 0) {
            #pragma unroll
            for (int x = 0; x < 4; ++x)
                #pragma unroll
                for (int y = 0; y < 4; ++y)
                    Pld[r4 + x][c4 + y] = P[x * 4 + y];
        }
        __syncthreads();
        if (wid == 1) {
            #pragma unroll
            for (int x = 0; x < 4; ++x)
                #pragma unroll
                for (int y = 0; y < 4; ++y)
                    Pld[r4 + x][c4 + y] = fmax(Pld[r4 + x][c4 + y], P[x * 4 + y]);
        }
        __syncthreads();
        if (wid == 2) {
            #pragma unroll
            for (int x = 0; x < 4; ++x)
                #pragma unroll
                for (int y = 0; y < 4; ++y)
                    Pld[r4 + x][c4 + y] = fmax(Pld[r4 + x][c4 + y], P[x * 4 + y]);
        }
        __syncthreads();
        if (wid == 3) {
            #pragma unroll
            for (int x = 0; x < 4; ++x)
                #pragma unroll
                for (int y = 0; y < 4; ++y)
                    Pld[r4 + x][c4 + y] = fmax(Pld[r4 + x][c4 + y], P[x * 4 + y]);
        }
        __syncthreads();
    } else {
        for (int idx = tid; idx < 32 * 33; idx += 256)
            ((double*)Pld)[idx] = 0.0;
        if (wid == 0) {
            if (lane < 33) edgeCol[lane] = ec;
            if (lane < 32) Vtc[lane][32] = ve;
        }
        __syncthreads();
    }

    if (wid == 0) {
        double vrow[16];
        #pragma unroll
        for (int u = 0; u < 16; ++u) vrow[u] = 0.0;

        double ecr = edgeCol[r];
        double ecp = edgeCol[r + 1];

        double tvA[16], qvA[16], tvB[16], qvB[16];
        double p1 = 0.0, shc = 0.0, shp = 0.0, erc = 0.0, erp = 0.0;

#define PREFB(TV, QV, SS)                                             \
    { int cc_ = (r + (SS) - 31) & 31;                                 \
      _Pragma("unroll")                                               \
      for (int u = 0; u < 16; ++u) {                                  \
          TV[u] = Vtc[cc_][h * 16 + u + 1];                           \
          QV[u] = DJJc[cc_][h * 16 + u + 1];                          \
      } }

#define STEPB(TV, QV, SS)                                             \
    { int c_ = r + (SS) - 31;                                         \
      bool act_ = ((unsigned)c_ < 32u);                               \
      int cc_ = c_ & 31;                                              \
      double er_  = Vtc[cc_][32];                                     \
      double dj0_ = DJJc[cc_][0];                                     \
      double pld_ = Pld[r][cc_];                                      \
      float  sld_ = Sld[r][cc_];                                      \
      shp = shc; erp = erc; erc = er_;                                \
      shc = __shfl_down(p1, 2);                                       \
      double acc_ = -1.0e30;                                          \
      if (act_) {                                                     \
          double t0_ = -1.0e30, t1_ = -1.0e30, t2_ = -1.0e30, t3_ = -1.0e30; \
          _Pragma("unroll")                                           \
          for (int u = 0; u < 16; u += 4) {                           \
              t0_ = fmax(t0_, aslice[u]     + TV[u]);                 \
              t1_ = fmax(t1_, aslice[u + 1] + TV[u + 1]);             \
              t2_ = fmax(t2_, aslice[u + 2] + TV[u + 2]);             \
              t3_ = fmax(t3_, aslice[u + 3] + TV[u + 3]);             \
          }                                                           \
          _Pragma("unroll")                                           \
          for (int u = 0; u < 16; u += 4) {                           \
              t0_ = fmax(t0_, vrow[u]     + QV[u]);                   \
              t1_ = fmax(t1_, vrow[u + 1] + QV[u + 1]);               \
              t2_ = fmax(t2_, vrow[u + 2] + QV[u + 2]);               \
              t3_ = fmax(t3_, vrow[u + 3] + QV[u + 3]);               \
          }                                                           \
          acc_ = fmax(fmax(t0_, t1_), fmax(t2_, t3_));                \
      }                                                               \
      acc_ = fmax(acc_, __shfl_xor(acc_, 1));                         \
      if (act_) {                                                     \
          double best_ = acc_;                                        \
          best_ = fmax(best_, (r == 31) ? erc : shc);                 \
          best_ = fmax(best_, ecr + dj0_);                            \
          best_ = fmax(best_, pld_);                                  \
          double pv_ = (c_ == 0) ? ecp : ((r == 31) ? erp : shp);     \
          best_ = fmax(best_, pv_ + (double)sld_);                    \
          if (h == 0) Vtc[c_][r] = best_;                             \
          _Pragma("unroll")                                           \
          for (int u = 0; u < 16; ++u)                                \
              if (h * 16 + u == c_) vrow[u] = best_;                  \
          p1 = best_;                                                 \
      } }

        PREFB(tvA, qvA, 0)
        for (int s2 = 0; s2 < 64; s2 += 2) {
            PREFB(tvB, qvB, s2 + 1)
            STEPB(tvA, qvA, s2)
            PREFB(tvA, qvA, s2 + 2)
            STEPB(tvB, qvB, s2 + 1)
        }
#undef PREFB
#undef STEPB
    }
    __syncthreads();

    #pragma unroll
    for (int w = 0; w < 4; ++w) {
        int idx = w * 256 + tid; int rr = idx >> 5, cc = idx & 31;
        gstore_cc(&R[(aI + rr) * NN + aJ + cc], Vtc[cc][rr]);
    }
    #pragma unroll
    for (int w = 0; w < 4; ++w) {
        int idx = w * 256 + tid; int cc = idx >> 5, rr = idx & 31;
        gstore_cc(&C[(aJ + cc) * NN + aI + rr], Vtc[cc][rr]);
    }
    VWAIT0;
    __syncthreads();
    if (tid == 0) gstore_flag(&flags[(I * TT + J) << 4], 1);
}

// ---------------------------------------------------------------------------
// Parallel traceback over independent split-segments (MALL work queue).
// Hardened: push = {qi/qj stores, vmcnt0, pending+1, vmcnt0, ready=1} so the
// pending counter is always >= outstanding work (sound termination); idle
// poll has a 2^22-iteration watchdog (clean exit instead of any hang).
// Pair set identical to reference: segments are disjoint nested intervals,
// each walk deterministic given (i,j) with v=R[i*NN+j]; out writes disjoint.
// ---------------------------------------------------------------------------
__global__ __launch_bounds__(256) void traceback_kernel(const double* __restrict__ R,
                                                        const double* __restrict__ C,
                                                        const float* __restrict__ S,
                                                        float* __restrict__ out,
                                                        int* __restrict__ qi,
                                                        int* __restrict__ qj,
                                                        int* __restrict__ qready,
                                                        int* __restrict__ qctl) {
    __shared__ double Rw[16][17];
    __shared__ float  Sw[16][17];
    __shared__ int sh_cmd, sh_i, sh_j;
    __shared__ double sred_v[4];
    __shared__ int sred_k[4];
    const double eps = 1e-9;
    const int tid = threadIdx.x;
    int* headp = qctl;
    int* tailp = qctl + 16;
    int* pendp = qctl + 32;

    int i = 0, j = 0; double v = 0.0;
    bool have = false;
    int ai = -(1 << 29), aj = 0;
    int myidx = -1;

    while (true) {
        if (tid == 0) {
            int cmd;
            int guard = 0;
            while (true) {
                if (!have) {
                    if (++guard > (1 << 22)) { cmd = -1; break; }   // watchdog
                    if (myidx < 0) myidx = atomicAdd(headp, 1);
                    int rdy = 0;
                    if (myidx < 4096)
                        rdy = __hip_atomic_load(&qready[myidx], __ATOMIC_RELAXED,
                                                __HIP_MEMORY_SCOPE_AGENT);
                    if (rdy) {
                        int ni, nj;
                        asm volatile("global_load_dword %0, %2, off sc0 sc1\n\t"
                                     "global_load_dword %1, %3, off sc0 sc1\n\t"
                                     "s_waitcnt vmcnt(0)"
                                     : "=&v"(ni), "=&v"(nj)
                                     : "v"(&qi[myidx]), "v"(&qj[myidx]));
                        myidx = -1;
                        i = ni; j = nj;
                        if (j <= i) { atomicAdd(pendp, -1); continue; }
                        v = R[i * NN + j];
                        if (v <= eps) { atomicAdd(pendp, -1); continue; }
                        have = true;
                        continue;
                    }
                    int pend = __hip_atomic_load(pendp, __ATOMIC_RELAXED,
                                                 __HIP_MEMORY_SCOPE_AGENT);
                    if (pend == 0) { cmd = -1; break; }
                    __builtin_amdgcn_s_sleep(2);
                    continue;
                }
                int u = i - ai, w = aj - j;
                if ((unsigned)u > 15u || (unsigned)w > 14u) { cmd = 1; break; }
                double a = Rw[u][w];                  // R[(i+1)*NN + j]
                if (a >= v - eps) {
                    ++i; v = a;
                    if (j <= i || v <= eps) { have = false; atomicAdd(pendp, -1); }
                    continue;
                }
                float sv = Sw[u][w];                  // S[i*NN + j]
                double b2 = Rw[u][w + 1];             // R[(i+1)*NN + j-1]
                if (sv > 0.0f && b2 + (double)sv >= v - eps) {
                    out[i * NN + j] = sv; out[j * NN + i] = sv;
                    ++i; --j; v = b2;
                    if (j <= i || v <= eps) { have = false; atomicAdd(pendp, -1); }
                    continue;
                }
                cmd = 0; break;                       // split
            }
            sh_cmd = cmd; sh_i = i; sh_j = j;
        }
        __syncthreads();
        int cmd = sh_cmd;
        if (cmd < 0) break;

        if (cmd == 1) {                               // refill window at (i,j)
            int i0 = sh_i, j0 = sh_j;
            int di = tid >> 4, dj = tid & 15;
            int rr = i0 + 1 + di; if (rr > NN - 1) rr = NN - 1;
            int cc = j0 - dj;     if (cc < 0) cc = 0;
            Rw[di][dj] = R[rr * NN + cc];
            int sr = i0 + di;     if (sr > NN - 1) sr = NN - 1;
            Sw[di][dj] = S[sr * NN + cc];
            __syncthreads();
            if (tid == 0) { ai = i0; aj = j0; }
            continue;
        }

        // cmd == 0: split via parallel argmax (first-max = smallest k)
        const int si = sh_i, sj = sh_j;
        double bv = -1.0; int bk = 0x7fffffff;
        for (int k = si + tid; k < sj; k += 256) {
            double tv = R[si * NN + k] + C[sj * NN + k + 1];
            if (tv > bv) { bv = tv; bk = k; }
        }
        for (int off = 32; off; off >>= 1) {
            double ov = __shfl_down(bv, off);
            int    ok = __shfl_down(bk, off);
            if (ov > bv || (ov == bv && ok < bk)) { bv = ov; bk = ok; }
        }
        if ((tid & 63) == 0) { sred_v[tid >> 6] = bv; sred_k[tid >> 6] = bk; }
        __syncthreads();
        if (tid == 0) {
            double fv = sred_v[0]; int fk = sred_k[0];
            for (int w = 1; w < 4; ++w)
                if (sred_v[w] > fv || (sred_v[w] == fv && sred_k[w] < fk)) { fv = sred_v[w]; fk = sred_k[w]; }
            // push right child (fk+1, sj): data -> pending -> ready, ordered
            int slot = atomicAdd(tailp, 1);
            int rv = fk + 1;
            asm volatile("global_store_dword %0, %1, off sc0 sc1" :: "v"(&qi[slot]), "v"(rv));
            asm volatile("global_store_dword %0, %1, off sc0 sc1" :: "v"(&qj[slot]), "v"(sj));
            VWAIT0;                                   // qi/qj at MALL
            atomicAdd(pendp, 1);
            VWAIT0;                                   // pending+1 at MALL
            gstore_flag(&qready[slot], 1);
            // continue inline with left child (si, fk)
            j = fk;                                   // i == si already
            if (j <= i) { have = false; atomicAdd(pendp, -1); }
            else {
                v = R[i * NN + j];
                if (v <= eps) { have = false; atomicAdd(pendp, -1); }
                else have = true;
            }
        }
        __syncthreads();
    }
}

// ---------------------------------------------------------------------------
extern "C" void kernel_launch(void* const* d_in, const int* in_sizes, int n_in,
                              void* d_out, int out_size, void* d_ws, size_t ws_size,
                              hipStream_t stream) {
    const float* con  = (const float*)d_in[0];
    const float* feat = (const float*)d_in[1];
    float* out = (float*)d_out;

    char* ws = (char*)d_ws;
    double* R      = (double*)(ws);
    double* C      = (double*)(ws + (size_t)8  * 1024 * 1024);
    float*  S      = (float*) (ws + (size_t)16 * 1024 * 1024);
    int*    primes = (int*)   (ws + (size_t)20 * 1024 * 1024);
    int*    flags  = (int*)   (ws + (size_t)20 * 1024 * 1024 + 8192);
    char*   qbase  = ws + (size_t)20 * 1024 * 1024 + 128 * 1024;
    int*    qi     = (int*)(qbase);
    int*    qj     = (int*)(qbase + 16 * 1024);
    int*    qready = (int*)(qbase + 32 * 1024);
    int*    qctl   = (int*)(qbase + 48 * 1024);

    primes_kernel<<<(NN + 255) / 256, 256, 0, stream>>>(feat, primes);
    prep_kernel<<<(NN * NN) / 256, 256, 0, stream>>>(con, primes, S, R, C, out, flags,
                                                     qi, qj, qready, qctl);
    nuss_tiles_kernel<<<NTILES, 256, 0, stream>>>(R, C, S, flags);
    traceback_kernel<<<64, 256, 0, stream>>>(R, C, S, out, qi, qj, qready, qctl);
}

// Round 10
// 1140.822 us; speedup vs baseline: 1.8414x; 1.1392x over previous
//
#include <hip/hip_runtime.h>

#define NN 1024
#define BT 32
#define TT 32
#define NTILES ((TT * (TT + 1)) / 2)   // 528

// ---------------------------------------------------------------------------
// Fence-free cross-XCD protocol (batched sc0sc1 MALL ops). Round-10:
// phaseB parallelized across ALL 4 waves: each wave computes 16 of the 64
// (max,+) terms per row-step (partials merged through LDS + 1 barrier/step);
// the cheap tail (edges/Pld/pair/select) is computed redundantly by every
// wave so the p1/vrow/shuffle state stays wave-local. Freshest terms (kk=r,
// kk=r+1) ride 1-step and 2-step delayed shuffles; prefetched terms need
// only rows >= r+3 whose LDS writes are >=1 barrier old => race-free.
// Traceback: round-9 parallel queue (verified). Exact term set preserved.
// ---------------------------------------------------------------------------
__device__ __forceinline__ double gload_cc(const double* p) {
    double v;
    asm volatile("global_load_dwordx2 %0, %1, off sc0 sc1" : "=v"(v) : "v"(p));
    return v;
}
__device__ __forceinline__ void gstore_cc(double* p, double v) {
    asm volatile("global_store_dwordx2 %0, %1, off sc0 sc1" :: "v"(p), "v"(v));
}
__device__ __forceinline__ void gstore_flag(int* p, int v) {
    asm volatile("global_store_dword %0, %1, off sc0 sc1" :: "v"(p), "v"(v));
}
#define VWAIT0 asm volatile("s_waitcnt vmcnt(0)" ::: "memory")

__device__ __forceinline__ void waitflag2(const int* f, int a0, int b0, int a1, int b1) {
    const int* p0 = &f[(a0 * TT + b0) << 4];
    const int* p1 = &f[(a1 * TT + b1) << 4];
    int it = 0;
    while (true) {
        int v0, v1;
        asm volatile("global_load_dword %0, %2, off sc0 sc1\n\t"
                     "global_load_dword %1, %3, off sc0 sc1\n\t"
                     "s_waitcnt vmcnt(0)"
                     : "=&v"(v0), "=&v"(v1)
                     : "v"(p0), "v"(p1));
        if (v0 & v1) break;
        if (it < 8) __builtin_amdgcn_s_sleep(1);
        else        __builtin_amdgcn_s_sleep(15);
        ++it;
    }
    asm volatile("" ::: "memory");
}
__device__ __forceinline__ void waitflag4(const int* f, int a0, int b0, int a1, int b1,
                                          int a2, int b2, int a3, int b3) {
    const int* p0 = &f[(a0 * TT + b0) << 4];
    const int* p1 = &f[(a1 * TT + b1) << 4];
    const int* p2 = &f[(a2 * TT + b2) << 4];
    const int* p3 = &f[(a3 * TT + b3) << 4];
    int it = 0;
    while (true) {
        int v0, v1, v2, v3;
        asm volatile("global_load_dword %0, %4, off sc0 sc1\n\t"
                     "global_load_dword %1, %5, off sc0 sc1\n\t"
                     "global_load_dword %2, %6, off sc0 sc1\n\t"
                     "global_load_dword %3, %7, off sc0 sc1\n\t"
                     "s_waitcnt vmcnt(0)"
                     : "=&v"(v0), "=&v"(v1), "=&v"(v2), "=&v"(v3)
                     : "v"(p0), "v"(p1), "v"(p2), "v"(p3));
        if (v0 & v1 & v2 & v3) break;
        if (it < 8) __builtin_amdgcn_s_sleep(1);
        else        __builtin_amdgcn_s_sleep(15);
        ++it;
    }
    asm volatile("" ::: "memory");
}
__device__ __forceinline__ void waitflag2_blk(const int* f, int a0, int b0, int a1, int b1) {
    if (threadIdx.x < 64) waitflag2(f, a0, b0, a1, b1);
    __syncthreads();
}
__device__ __forceinline__ void waitflag4_blk(const int* f, int a0, int b0, int a1, int b1,
                                              int a2, int b2, int a3, int b3) {
    if (threadIdx.x < 64) waitflag4(f, a0, b0, a1, b1, a2, b2, a3, b3);
    __syncthreads();
}

// ---------------------------------------------------------------------------
__global__ void primes_kernel(const float* __restrict__ feat, int* __restrict__ primes) {
    int i = blockIdx.x * blockDim.x + threadIdx.x;
    if (i < NN) {
        float best = feat[i * NN];
        int arg = 0;
        for (int ch = 1; ch < 4; ++ch) {
            float v = feat[ch * NN * NN + i * NN];
            if (v > best) { best = v; arg = ch; }
        }
        const int P[4] = {2, 3, 5, 7};
        primes[i] = P[arg];
    }
}

__global__ void prep_kernel(const float* __restrict__ con, const int* __restrict__ primes,
                            float* __restrict__ S, double* __restrict__ R,
                            double* __restrict__ C, float* __restrict__ out,
                            int* __restrict__ flags,
                            int* __restrict__ qi, int* __restrict__ qj,
                            int* __restrict__ qready, int* __restrict__ qctl) {
    int idx = blockIdx.x * blockDim.x + threadIdx.x;
    int i = idx >> 10;
    int j = idx & (NN - 1);
    float c = (con[idx] + con[j * NN + i]) * 0.5f;
    int prod = primes[i] * primes[j];
    bool canon = (prod == 14) | (prod == 15) | (prod == 35);
    int d = i - j; if (d < 0) d = -d;
    S[idx] = (canon && d >= 4) ? c : 0.0f;
    R[idx] = 0.0;
    C[idx] = 0.0;
    out[idx] = 0.0f;
    if (idx < TT * TT * 16) flags[idx] = 0;
    if (idx < 4096) qready[idx] = (idx == 0) ? 1 : 0;
    if (idx == 0) {
        qi[0] = 0; qj[0] = NN - 1;
        qctl[0] = 0;      // head
        qctl[16] = 1;     // tail
        qctl[32] = 1;     // pending
    }
}

// ---------------------------------------------------------------------------
// Dataflow DP, 4 waves per 32x32 tile. Exactness: every candidate is one
// fp64 add of stored values; extra candidates are dominated (-1e30+x<0<=dp,
// stale-0 + 0 = 0 <= dp); fmax is exact => bitwise == numpy.
// phaseB 4-wave split: term kk=r -> shfl(p1,2); kk=r+1 -> shfl(p2,4) with
// p2 shifted unconditionally (valid when source lane deactivates); r==30
// uses the static edge row, r==31 has no kk=r+1 term. Prefetched terms
// (kk>r+1, i.e. rows>=r+3) read LDS written >=1 barrier earlier.
// ---------------------------------------------------------------------------
__global__ __launch_bounds__(256) void nuss_tiles_kernel(double* __restrict__ R,
                                                         double* __restrict__ C,
                                                         const float* __restrict__ S,
                                                         int* __restrict__ flags) {
    __shared__ double DJJc[32][33];
    __shared__ double Vtc[32][33];
    __shared__ __attribute__((aligned(16))) double Ast[32][34];
    __shared__ __attribute__((aligned(16))) double Bst[32][34];
    __shared__ double Pld[32][33];
    __shared__ float  Sld[32][32];
    __shared__ double edgeCol[33];
    __shared__ double Prt[2][4][32];                 // per-step wave partials

    int b = blockIdx.x, dd = 0;
    while (b >= TT - dd) { b -= TT - dd; ++dd; }
    const int I = b, J = b + dd;
    const int aI = I * BT, aJ = J * BT;
    const int tid = threadIdx.x;
    const int wid = tid >> 6;
    const int lane = tid & 63;
    const int r = lane >> 1;
    const int h = lane & 1;

    if (dd == 0) {
        #pragma unroll
        for (int w = 0; w < 4; ++w) {
            int idx = w * 256 + tid; int rr = idx >> 5, cc = idx & 31;
            Sld[rr][cc] = S[(aI + rr) * NN + aI + cc];
        }
        for (int idx = tid; idx < 32 * 33; idx += 256)
            ((double*)Vtc)[idx] = 0.0;
        __syncthreads();
        if (wid == 0) {
            double vrow[16];
            #pragma unroll
            for (int u = 0; u < 16; ++u) vrow[u] = 0.0;
            for (int s = 1; s <= 31; ++s) {
                int c = r + s;
                bool act = (c <= 31);
                double acc = 0.0;
                if (act) {
                    double t0 = 0.0, t1 = 0.0, t2 = 0.0, t3 = 0.0;
                    #pragma unroll
                    for (int u = 0; u < 16; u += 4) {
                        int k0 = h * 16 + u;
                        t0 = fmax(t0, vrow[u]     + Vtc[c][k0 + 1]);
                        t1 = fmax(t1, vrow[u + 1] + Vtc[c][k0 + 2]);
                        t2 = fmax(t2, vrow[u + 2] + Vtc[c][k0 + 3]);
                        t3 = fmax(t3, vrow[u + 3] + Vtc[c][k0 + 4]);
                    }
                    acc = fmax(fmax(t0, t1), fmax(t2, t3));
                }
                acc = fmax(acc, __shfl_xor(acc, 1));
                if (act) {
                    double best = fmax(acc, Vtc[c - 1][r + 1] + (double)Sld[r][c]);
                    if (h == 0) Vtc[c][r] = best;
                    #pragma unroll
                    for (int u = 0; u < 16; ++u)
                        if (h * 16 + u == c) vrow[u] = best;
                }
            }
        }
        __syncthreads();
        #pragma unroll
        for (int w = 0; w < 4; ++w) {
            int idx = w * 256 + tid; int rr = idx >> 5, cc = idx & 31;
            gstore_cc(&R[(aI + rr) * NN + aI + cc], Vtc[cc][rr]);
        }
        #pragma unroll
        for (int w = 0; w < 4; ++w) {
            int idx = w * 256 + tid; int cc = idx >> 5, rr = idx & 31;
            gstore_cc(&C[(aI + cc) * NN + aI + rr], Vtc[cc][rr]);
        }
        VWAIT0;
        __syncthreads();
        if (tid == 0) gstore_flag(&flags[(I * TT + I) << 4], 1);
        return;
    }

    // ---------------- off-diagonal tile ----------------
    const int nk = dd - 1;
    const int off = (wid & 1) * 16 + h * 8;          // this lane's 8-term slice
    waitflag2_blk(flags, I, I, J, J);

    double ra[4], rb[4];
    double ec = 0.0, ve = 0.0;
    double asl[8];
    double ar1 = 0.0;
    #pragma unroll
    for (int w = 0; w < 4; ++w) {
        int idx = w * 256 + tid; int cc = idx >> 5, mm = idx & 31;
        ra[w] = gload_cc(&C[(aJ + cc) * NN + aJ + mm]);
    }
    if (wid < 2) {
        #pragma unroll
        for (int u = 0; u < 8; ++u)
            asl[u] = gload_cc(&R[(aI + r) * NN + aI + off + u]);
    }
    if (r < 31) ar1 = gload_cc(&R[(aI + r) * NN + aI + r + 1]);
    if (wid == 0 && nk == 0) {
        if (lane < 33) ec = gload_cc(&R[(aI + lane) * NN + (aJ - 1)]);
        if (lane < 32) ve = gload_cc(&R[(aI + 32) * NN + aJ + lane]);
    }
    #pragma unroll
    for (int w = 0; w < 4; ++w) {
        int idx = w * 256 + tid; int rr = idx >> 5, cc = idx & 31;
        Sld[rr][cc] = S[(aI + rr) * NN + aJ + cc];
    }
    for (int idx = tid; idx < 32 * 33; idx += 256)
        ((double*)Vtc)[idx] = 0.0;
    VWAIT0;
    #pragma unroll
    for (int w = 0; w < 4; ++w) {
        int idx = w * 256 + tid; int cc = idx >> 5, mm = idx & 31;
        DJJc[cc][mm] = ra[w];
    }
    if (tid < 32) DJJc[tid][32] = 0.0;
    // slice8: aslice (waves 0,1; guard kk>r+1) or vrow (waves 2,3; init 0)
    double slice8[8];
    if (wid < 2) {
        #pragma unroll
        for (int u = 0; u < 8; ++u)
            slice8[u] = (off + u > r + 1) ? asl[u] : -1.0e30;
    } else {
        #pragma unroll
        for (int u = 0; u < 8; ++u) slice8[u] = 0.0;
    }
    if (wid == 0 && nk == 0) {
        if (lane < 33) edgeCol[lane] = ec;
        if (lane < 32) Vtc[lane][32] = ve;
    }
    __syncthreads();

    // ---- phaseA: all-wave cooperative, middle-out, readiness pairs ----
    double P[16];
    #pragma unroll
    for (int x = 0; x < 16; ++x) P[x] = 0.0;
    const int rg = lane >> 3, cg = lane & 7;
    const int r4 = rg * 4, c4 = cg * 4;

    auto kkloop = [&]() {
        for (int kk = wid * 8; kk < wid * 8 + 8; ++kk) {
            double2 av0 = *(const double2*)&Ast[kk][r4];
            double2 av1 = *(const double2*)&Ast[kk][r4 + 2];
            double2 bv0 = *(const double2*)&Bst[kk][c4];
            double2 bv1 = *(const double2*)&Bst[kk][c4 + 2];
            P[0]  = fmax(P[0],  av0.x + bv0.x); P[1]  = fmax(P[1],  av0.x + bv0.y);
            P[2]  = fmax(P[2],  av0.x + bv1.x); P[3]  = fmax(P[3],  av0.x + bv1.y);
            P[4]  = fmax(P[4],  av0.y + bv0.x); P[5]  = fmax(P[5],  av0.y + bv0.y);
            P[6]  = fmax(P[6],  av0.y + bv1.x); P[7]  = fmax(P[7],  av0.y + bv1.y);
            P[8]  = fmax(P[8],  av1.x + bv0.x); P[9]  = fmax(P[9],  av1.x + bv0.y);
            P[10] = fmax(P[10], av1.x + bv1.x); P[11] = fmax(P[11], av1.x + bv1.y);
            P[12] = fmax(P[12], av1.y + bv0.x); P[13] = fmax(P[13], av1.y + bv0.y);
            P[14] = fmax(P[14], av1.y + bv1.x); P[15] = fmax(P[15], av1.y + bv1.y);
        }
    };
    auto proc = [&](int t1, int t2, bool last) {
        if (t2 >= 0) waitflag4_blk(flags, I, t1, t1, J, I, t2, t2, J);
        else         waitflag2_blk(flags, I, t1, t1, J);
        if (last && wid == 0) {
            if (lane < 33) ec = gload_cc(&R[(aI + lane) * NN + (aJ - 1)]);
            if (lane < 32) ve = gload_cc(&R[(aI + 32) * NN + aJ + lane]);
        }
        int k1 = t1 * BT;
        #pragma unroll
        for (int w = 0; w < 4; ++w) {
            int idx = w * 256 + tid; int rr = idx >> 5, kk = idx & 31;
            ra[w] = gload_cc(&R[(aI + rr) * NN + k1 + kk]);
            rb[w] = gload_cc(&C[(aJ + rr) * NN + k1 + 1 + kk]);
        }
        VWAIT0;
        #pragma unroll
        for (int w = 0; w < 4; ++w) {
            int idx = w * 256 + tid; int rr = idx >> 5, kk = idx & 31;
            Ast[kk][rr] = ra[w];
            Bst[kk][rr] = rb[w];
        }
        if (last && wid == 0) {
            if (lane < 33) edgeCol[lane] = ec;
            if (lane < 32) Vtc[lane][32] = ve;
        }
        __syncthreads();
        if (t2 >= 0) {
            int k2 = t2 * BT;
            #pragma unroll
            for (int w = 0; w < 4; ++w) {
                int idx = w * 256 + tid; int rr = idx >> 5, kk = idx & 31;
                ra[w] = gload_cc(&R[(aI + rr) * NN + k2 + kk]);
                rb[w] = gload_cc(&C[(aJ + rr) * NN + k2 + 1 + kk]);
            }
        }
        kkloop();
        if (t2 >= 0) {
            __syncthreads();
            VWAIT0;
            #pragma unroll
            for (int w = 0; w < 4; ++w) {
                int idx = w * 256 + tid; int rr = idx >> 5, kk = idx & 31;
                Ast[kk][rr] = ra[w];
                Bst[kk][rr] = rb[w];
            }
            __syncthreads();
            kkloop();
        }
        __syncthreads();
    };

    {
        int tl = (I + J) >> 1, tr = ((I + J) >> 1) + 1;
        int pend = -1;
        for (int q = 0; q < nk; ++q) {
            int t;
            if ((q & 1) == 0) { if (tl >= I + 1) t = tl--; else t = tr++; }
            else              { if (tr <= J - 1) t = tr++; else t = tl--; }
            if (pend < 0) { pend = t; continue; }
            int rp = (pend - I > J - pend) ? pend - I : J - pend;
            int rt = (t - I > J - t) ? t - I : J - t;
            if (rp == rt) { proc(pend, t, q == nk - 1); pend = -1; }
            else          { proc(pend, -1, false); pend = t; }
        }
        if (pend >= 0) proc(pend, -1, true);
    }

    // ---- Pld merge (exact fmax, fixed barrier order) ----
    if (nk > 0) {
        if (wid == 0) {
            #pragma unroll
            for (int x = 0; x < 4; ++x)
                #pragma unroll
                for (int y = 0; y < 4; ++y)
                    Pld[r4 + x][c4 + y] = P[x * 4 + y];
        }
        __syncthreads();
        if (wid == 1) {
            #pragma unroll
            for (int x = 0; x < 4; ++x)
                #pragma unroll
                for (int y = 0; y < 4; ++y)
                    Pld[r4 + x][c4 + y] = fmax(Pld[r4 + x][c4 + y], P[x * 4 + y]);
        }
        __syncthreads();
        if (wid == 2) {
            #pragma unroll
            for (int x = 0; x < 4; ++x)
                #pragma unroll
                for (int y = 0; y < 4; ++y)
                    Pld[r4 + x][c4 + y] = fmax(Pld[r4 + x][c4 + y], P[x * 4 + y]);
        }
        __syncthreads();
        if (wid == 3) {
            #pragma unroll
            for (int x = 0; x < 4; ++x)
                #pragma unroll
                for (int y = 0; y < 4; ++y)
                    Pld[r4 + x][c4 + y] = fmax(Pld[r4 + x][c4 + y], P[x * 4 + y]);
        }
        __syncthreads();
    } else {
        for (int idx = tid; idx < 32 * 33; idx += 256)
            ((double*)Pld)[idx] = 0.0;
        __syncthreads();
    }

    // ---- phaseB: 4-wave k-split, 1 barrier/step, redundant tail ----
    {
        const double* bsel = (wid < 2) ? &Vtc[0][0] : &DJJc[0][0];
        double ecr = edgeCol[r];
        double ecp = edgeCol[r + 1];
        double pA[8], pB[8];
        double p1 = 0.0, p2 = 0.0, shc = 0.0, shp = 0.0, erc = 0.0, erp = 0.0;

#define PREFQ(PV, SS)                                                 \
    { int cq_ = (r + (SS) - 31) & 31;                                 \
      const double* bp_ = bsel + cq_ * 33 + off + 1;                  \
      _Pragma("unroll")                                               \
      for (int u = 0; u < 8; ++u) PV[u] = bp_[u]; }

#define STEPQ(PV, SS, BUF)                                            \
    { int c_ = r + (SS) - 31;                                         \
      bool act_ = ((unsigned)c_ < 32u);                               \
      int cc_ = c_ & 31;                                              \
      double t0_ = fmax(slice8[0] + PV[0], slice8[1] + PV[1]);        \
      double t1_ = fmax(slice8[2] + PV[2], slice8[3] + PV[3]);        \
      double t2_ = fmax(slice8[4] + PV[4], slice8[5] + PV[5]);        \
      double t3_ = fmax(slice8[6] + PV[6], slice8[7] + PV[7]);        \
      double pa_ = fmax(fmax(t0_, t1_), fmax(t2_, t3_));              \
      pa_ = fmax(pa_, __shfl_xor(pa_, 1));                            \
      if (h == 0) Prt[BUF][wid][r] = pa_;                             \
      __syncthreads();                                                \
      double a0_ = Prt[BUF][0][r];                                    \
      double a1_ = Prt[BUF][1][r];                                    \
      double a2_ = Prt[BUF][2][r];                                    \
      double a3_ = Prt[BUF][3][r];                                    \
      double er_  = Vtc[cc_][32];                                     \
      double dj0_ = DJJc[cc_][0];                                     \
      double pld_ = Pld[r][cc_];                                      \
      float  sld_ = Sld[r][cc_];                                      \
      shp = shc; erp = erc; erc = er_;                                \
      shc = __shfl_down(p1, 2);                                       \
      double shd_ = __shfl_down(p2, 4);                               \
      p2 = p1;                                                        \
      double acc_ = fmax(fmax(a0_, a1_), fmax(a2_, a3_));             \
      if (act_) {                                                     \
          double best_ = acc_;                                        \
          best_ = fmax(best_, (r == 31) ? erc : shc);                 \
          if (r < 31)                                                 \
              best_ = fmax(best_, ar1 + ((r == 30) ? erc : shd_));    \
          best_ = fmax(best_, ecr + dj0_);                            \
          best_ = fmax(best_, pld_);                                  \
          double pv_ = (c_ == 0) ? ecp : ((r == 31) ? erp : shp);     \
          best_ = fmax(best_, pv_ + (double)sld_);                    \
          if (wid == 0 && h == 0) Vtc[c_][r] = best_;                 \
          if (wid >= 2) {                                             \
              _Pragma("unroll")                                       \
              for (int u = 0; u < 8; ++u)                             \
                  if (off + u == c_) slice8[u] = best_;               \
          }                                                           \
          p1 = best_;                                                 \
      } }

        PREFQ(pA, 0)
        PREFQ(pB, 1)
        for (int s2 = 0; s2 < 64; s2 += 2) {
            STEPQ(pA, s2, 0)
            PREFQ(pA, s2 + 2)
            STEPQ(pB, s2 + 1, 1)
            PREFQ(pB, s2 + 3)
        }
#undef PREFQ
#undef STEPQ
    }
    __syncthreads();

    // ---- writeback, 4-way split ----
    #pragma unroll
    for (int w = 0; w < 4; ++w) {
        int idx = w * 256 + tid; int rr = idx >> 5, cc = idx & 31;
        gstore_cc(&R[(aI + rr) * NN + aJ + cc], Vtc[cc][rr]);
    }
    #pragma unroll
    for (int w = 0; w < 4; ++w) {
        int idx = w * 256 + tid; int cc = idx >> 5, rr = idx & 31;
        gstore_cc(&C[(aJ + cc) * NN + aI + rr], Vtc[cc][rr]);
    }
    VWAIT0;
    __syncthreads();
    if (tid == 0) gstore_flag(&flags[(I * TT + J) << 4], 1);
}

// ---------------------------------------------------------------------------
// Parallel traceback over independent split-segments (round-9, verified).
// ---------------------------------------------------------------------------
__global__ __launch_bounds__(256) void traceback_kernel(const double* __restrict__ R,
                                                        const double* __restrict__ C,
                                                        const float* __restrict__ S,
                                                        float* __restrict__ out,
                                                        int* __restrict__ qi,
                                                        int* __restrict__ qj,
                                                        int* __restrict__ qready,
                                                        int* __restrict__ qctl) {
    __shared__ double Rw[16][17];
    __shared__ float  Sw[16][17];
    __shared__ int sh_cmd, sh_i, sh_j;
    __shared__ double sred_v[4];
    __shared__ int sred_k[4];
    const double eps = 1e-9;
    const int tid = threadIdx.x;
    int* headp = qctl;
    int* tailp = qctl + 16;
    int* pendp = qctl + 32;

    int i = 0, j = 0; double v = 0.0;
    bool have = false;
    int ai = -(1 << 29), aj = 0;
    int myidx = -1;

    while (true) {
        if (tid == 0) {
            int cmd;
            int guard = 0;
            while (true) {
                if (!have) {
                    if (++guard > (1 << 22)) { cmd = -1; break; }   // watchdog
                    if (myidx < 0) myidx = atomicAdd(headp, 1);
                    int rdy = 0;
                    if (myidx < 4096)
                        rdy = __hip_atomic_load(&qready[myidx], __ATOMIC_RELAXED,
                                                __HIP_MEMORY_SCOPE_AGENT);
                    if (rdy) {
                        int ni, nj;
                        asm volatile("global_load_dword %0, %2, off sc0 sc1\n\t"
                                     "global_load_dword %1, %3, off sc0 sc1\n\t"
                                     "s_waitcnt vmcnt(0)"
                                     : "=&v"(ni), "=&v"(nj)
                                     : "v"(&qi[myidx]), "v"(&qj[myidx]));
                        myidx = -1;
                        i = ni; j = nj;
                        if (j <= i) { atomicAdd(pendp, -1); continue; }
                        v = R[i * NN + j];
                        if (v <= eps) { atomicAdd(pendp, -1); continue; }
                        have = true;
                        continue;
                    }
                    int pend = __hip_atomic_load(pendp, __ATOMIC_RELAXED,
                                                 __HIP_MEMORY_SCOPE_AGENT);
                    if (pend == 0) { cmd = -1; break; }
                    __builtin_amdgcn_s_sleep(2);
                    continue;
                }
                int u = i - ai, w = aj - j;
                if ((unsigned)u > 15u || (unsigned)w > 14u) { cmd = 1; break; }
                double a = Rw[u][w];                  // R[(i+1)*NN + j]
                if (a >= v - eps) {
                    ++i; v = a;
                    if (j <= i || v <= eps) { have = false; atomicAdd(pendp, -1); }
                    continue;
                }
                float sv = Sw[u][w];                  // S[i*NN + j]
                double b2 = Rw[u][w + 1];             // R[(i+1)*NN + j-1]
                if (sv > 0.0f && b2 + (double)sv >= v - eps) {
                    out[i * NN + j] = sv; out[j * NN + i] = sv;
                    ++i; --j; v = b2;
                    if (j <= i || v <= eps) { have = false; atomicAdd(pendp, -1); }
                    continue;
                }
                cmd = 0; break;                       // split
            }
            sh_cmd = cmd; sh_i = i; sh_j = j;
        }
        __syncthreads();
        int cmd = sh_cmd;
        if (cmd < 0) break;

        if (cmd == 1) {                               // refill window at (i,j)
            int i0 = sh_i, j0 = sh_j;
            int di = tid >> 4, dj = tid & 15;
            int rr = i0 + 1 + di; if (rr > NN - 1) rr = NN - 1;
            int cc = j0 - dj;     if (cc < 0) cc = 0;
            Rw[di][dj] = R[rr * NN + cc];
            int sr = i0 + di;     if (sr > NN - 1) sr = NN - 1;
            Sw[di][dj] = S[sr * NN + cc];
            __syncthreads();
            if (tid == 0) { ai = i0; aj = j0; }
            continue;
        }

        // cmd == 0: split via parallel argmax (first-max = smallest k)
        const int si = sh_i, sj = sh_j;
        double bv = -1.0; int bk = 0x7fffffff;
        for (int k = si + tid; k < sj; k += 256) {
            double tv = R[si * NN + k] + C[sj * NN + k + 1];
            if (tv > bv) { bv = tv; bk = k; }
        }
        for (int offr = 32; offr; offr >>= 1) {
            double ov = __shfl_down(bv, offr);
            int    ok = __shfl_down(bk, offr);
            if (ov > bv || (ov == bv && ok < bk)) { bv = ov; bk = ok; }
        }
        if ((tid & 63) == 0) { sred_v[tid >> 6] = bv; sred_k[tid >> 6] = bk; }
        __syncthreads();
        if (tid == 0) {
            double fv = sred_v[0]; int fk = sred_k[0];
            for (int w = 1; w < 4; ++w)
                if (sred_v[w] > fv || (sred_v[w] == fv && sred_k[w] < fk)) { fv = sred_v[w]; fk = sred_k[w]; }
            // push right child (fk+1, sj): data -> pending -> ready, ordered
            int slot = atomicAdd(tailp, 1);
            int rv = fk + 1;
            asm volatile("global_store_dword %0, %1, off sc0 sc1" :: "v"(&qi[slot]), "v"(rv));
            asm volatile("global_store_dword %0, %1, off sc0 sc1" :: "v"(&qj[slot]), "v"(sj));
            VWAIT0;                                   // qi/qj at MALL
            atomicAdd(pendp, 1);
            VWAIT0;                                   // pending+1 at MALL
            gstore_flag(&qready[slot], 1);
            // continue inline with left child (si, fk)
            j = fk;                                   // i == si already
            if (j <= i) { have = false; atomicAdd(pendp, -1); }
            else {
                v = R[i * NN + j];
                if (v <= eps) { have = false; atomicAdd(pendp, -1); }
                else have = true;
            }
        }
        __syncthreads();
    }
}

// ---------------------------------------------------------------------------
extern "C" void kernel_launch(void* const* d_in, const int* in_sizes, int n_in,
                              void* d_out, int out_size, void* d_ws, size_t ws_size,
                              hipStream_t stream) {
    const float* con  = (const float*)d_in[0];
    const float* feat = (const float*)d_in[1];
    float* out = (float*)d_out;

    char* ws = (char*)d_ws;
    double* R      = (double*)(ws);
    double* C      = (double*)(ws + (size_t)8  * 1024 * 1024);
    float*  S      = (float*) (ws + (size_t)16 * 1024 * 1024);
    int*    primes = (int*)   (ws + (size_t)20 * 1024 * 1024);
    int*    flags  = (int*)   (ws + (size_t)20 * 1024 * 1024 + 8192);
    char*   qbase  = ws + (size_t)20 * 1024 * 1024 + 128 * 1024;
    int*    qi     = (int*)(qbase);
    int*    qj     = (int*)(qbase + 16 * 1024);
    int*    qready = (int*)(qbase + 32 * 1024);
    int*    qctl   = (int*)(qbase + 48 * 1024);

    primes_kernel<<<(NN + 255) / 256, 256, 0, stream>>>(feat, primes);
    prep_kernel<<<(NN * NN) / 256, 256, 0, stream>>>(con, primes, S, R, C, out, flags,
                                                     qi, qj, qready, qctl);
    nuss_tiles_kernel<<<NTILES, 256, 0, stream>>>(R, C, S, flags);
    traceback_kernel<<<64, 256, 0, stream>>>(R, C, S, out, qi, qj, qready, qctl);
}